// Round 3
// baseline (488.056 us; speedup 1.0000x reference)
//
#include <hip/hip_runtime.h>
#include <math.h>

// Problem constants
#define NTOT 16384        // N = B*T
#define GG 2
#define MM 1024
#define DD 256

// Output layout (flat float32)
#define OFF_Q  ((size_t)0)
#define OFF_CP ((size_t)8388608)
#define OFF_PP ((size_t)8388610)
#define OFF_I  ((size_t)8388612)
#define OFF_L  ((size_t)8421380)

#define SHIFT 40.0f       // row-constant logit shift (softmax/argmax invariant)
#define REFINE_GAP 0.03f  // fp64 re-check threshold (fast-log z err << this)

typedef __attribute__((ext_vector_type(8))) short bf16x8;
typedef __attribute__((ext_vector_type(4))) float f32x4;
typedef unsigned short u16;
typedef unsigned int u32;

__device__ inline float wave_sum_f(float v) {
#pragma unroll
  for (int o = 32; o > 0; o >>= 1) v += __shfl_xor(v, o);
  return v;
}
__device__ inline u16 f2bf(float f) {
  u32 u = __float_as_uint(f);
  return (u16)((u + 0x7fffu + ((u >> 16) & 1u)) >> 16);
}
__device__ inline float bf2f(u16 h) {
  return __uint_as_float(((u32)h) << 16);
}
// async 16B global->LDS (LDS dest = wave-uniform base + lane*16)
__device__ inline void async16(const void* g, void* l) {
  __builtin_amdgcn_global_load_lds(
      (const __attribute__((address_space(1))) u32*)g,
      (__attribute__((address_space(3))) u32*)l, 16, 0, 0);
}
// -ln(u), accurate for u -> 1 (series) and u small (hw log).
__device__ inline float neg_log_acc(float u) {
  float t1 = 1.0f - u;
  float se = t1 * (1.f + t1 * (0.5f + t1 * (0.33333334f + t1 * 0.25f)));
  float fl = -__logf(u);
  return (t1 < 0.015625f) ? se : fl;
}

// ============ ws layout (v3) ============
// 0       sq_e f32[2048]
// 8192    avg  f32[2048]
// 16384   hist i32[2048]
// 24576   loss double
// 32768   invZ f32[2*16384]          (128KB)
// 163840  eh_sw u16[2*1024*256]      (1MB, MFMA-frag swizzled)
// 1212416 el_sw u16[2*1024*256]      (1MB)
// 2260992 est  u16[2*1024*16384]     (67MB, [g][m][n] bf16)
#define WS_INVZ   32768
#define WS_EHSW   163840
#define WS_ELSW   1212416
#define WS_EST    2260992
#define WS_NEED3  (2260992ull + 2ull * MM * (size_t)NTOT * GG)

// ---- init A: sq_e + zero hist/loss (+ optional row-major hi/lo for fallback)
__global__ void vq_init2(const float* __restrict__ emb, float* __restrict__ sq_e,
                         float* __restrict__ avg, int* __restrict__ hist,
                         double* __restrict__ loss, u16* __restrict__ eh,
                         u16* __restrict__ el, int do_split) {
  const int row = blockIdx.x * 4 + (threadIdx.x >> 6);
  const int lane = threadIdx.x & 63;
  float4 e4 = *(const float4*)&emb[(size_t)row * DD + lane * 4];
  float s = e4.x * e4.x + e4.y * e4.y + e4.z * e4.z + e4.w * e4.w;
  s = wave_sum_f(s);
  if (do_split) {
    ushort4 h, l;
    h.x = f2bf(e4.x); l.x = f2bf(e4.x - bf2f(h.x));
    h.y = f2bf(e4.y); l.y = f2bf(e4.y - bf2f(h.y));
    h.z = f2bf(e4.z); l.z = f2bf(e4.z - bf2f(h.z));
    h.w = f2bf(e4.w); l.w = f2bf(e4.w - bf2f(h.w));
    *(ushort4*)&eh[(size_t)row * DD + lane * 4] = h;
    *(ushort4*)&el[(size_t)row * DD + lane * 4] = l;
  }
  if (lane == 0) sq_e[row] = s;
  if (blockIdx.x == 0) {
    for (int i = threadIdx.x; i < GG * MM; i += 256) { avg[i] = 0.f; hist[i] = 0; }
    if (threadIdx.x == 0) *loss = 0.0;
  }
}

// ---- init B: build swizzled hi/lo tables in MFMA-frag chunk order.
// chunk(g,ct,ks,cg,quad,l15) = B[col=ct*64+cg*16+l15][k=ks*32+quad*8 .. +8]
// linear chunk idx = (((g*16+ct)*8+ks)*4+cg)*64 + quad*16 + l15, 16B each.
__global__ void vq_init_swz(const float* __restrict__ emb, u16* __restrict__ eh_sw,
                            u16* __restrict__ el_sw) {
  int tid = blockIdx.x * 256 + threadIdx.x;   // 0..65535
  int g = tid >> 15, rem = tid & 32767;
  int col = rem >> 5, kc = rem & 31;          // kc: 8-element k-chunk
  const float* src = emb + ((size_t)(g * MM + col)) * DD + kc * 8;
  float4 fa = *(const float4*)src;
  float4 fb = *(const float4*)(src + 4);
  float f[8] = {fa.x, fa.y, fa.z, fa.w, fb.x, fb.y, fb.z, fb.w};
  u16 hi[8], lo[8];
#pragma unroll
  for (int j = 0; j < 8; ++j) {
    hi[j] = f2bf(f[j]);
    lo[j] = f2bf(f[j] - bf2f(hi[j]));
  }
  int ct = col >> 6, cg = (col >> 4) & 3, l15 = col & 15;
  int ks = kc >> 2, quad = kc & 3;
  size_t chunk = ((((size_t)g * 16 + ct) * 8 + ks) * 4 + cg) * 64 + quad * 16 + l15;
  ushort4* dh = (ushort4*)(eh_sw + chunk * 8);
  ushort4* dl = (ushort4*)(el_sw + chunk * 8);
  dh[0] = make_ushort4(hi[0], hi[1], hi[2], hi[3]);
  dh[1] = make_ushort4(hi[4], hi[5], hi[6], hi[7]);
  dl[0] = make_ushort4(lo[0], lo[1], lo[2], lo[3]);
  dl[1] = make_ushort4(lo[4], lo[5], lo[6], lo[7]);
}

// ---- main v6: 128 rows/block, 512 thr = 8 waves = 8 strips x 16 rows.
// Each wave sweeps all 1024 m over 32-col double-buffered tiles (64KB LDS ->
// 2 blocks/CU, 4 waves/SIMD). est writes per m cover 256B contiguous within
// one block/barrier epoch (no partial-sector RMW). A-frags built from direct
// global loads (no x LDS stage). Fast __expf/__logf (refine catches ties).
__global__ __launch_bounds__(512, 4) void vq_main3(
    const float* __restrict__ x, const float* __restrict__ emb,
    const float* __restrict__ gum, const float* __restrict__ sq_e,
    const u16* __restrict__ eh_sw, const u16* __restrict__ el_sw,
    float* __restrict__ out, u16* __restrict__ est, float* __restrict__ invZ_ws,
    int* __restrict__ hist, double* __restrict__ loss) {
  __shared__ u16 bt[2][16384];     // 2 x 32KB tile buffers
  __shared__ int fidx_lds[128];

  const int g = blockIdx.y;
  const int n0 = blockIdx.x * 128;
  const int t = threadIdx.x;
  const int wave = t >> 6, lane = t & 63;
  const int quad = lane >> 4, l15 = lane & 15;
  const int nw = n0 + wave * 16;   // this wave's first row

  const u16* sgh = eh_sw + (size_t)g * 16 * 16384;  // 16 chunks x 16384 u16
  const u16* sgl = el_sw + (size_t)g * 16 * 16384;

  // tile t32 = 32 cols: ct = t32>>1, cg pair base pb = (t32&1)*2.
  // 16 hi slices + 16 lo slices of 1KB; each wave stages 2+2.
  auto stage = [&](int t32, int buf) {
    int ct = t32 >> 1, pb = (t32 & 1) * 2;
    const u16* sh = sgh + (size_t)ct * 16384;
    const u16* sl = sgl + (size_t)ct * 16384;
    u16* dh = &bt[buf][0];
    u16* dl = &bt[buf][8192];
#pragma unroll
    for (int j = 0; j < 2; ++j) {
      int slot = j * 8 + wave;            // 0..15
      int ks = slot >> 1, cgp = slot & 1;
      int so = (ks * 4 + pb + cgp) * 512;
      async16(sh + so + lane * 8, dh + slot * 512);
      async16(sl + so + lane * 8, dl + slot * 512);
    }
  };

  stage(0, 0);   // overlap with A-frag global loads below

  // ---- build A fragments from global (16 rows, 8 k-steps, hi+lo split) ----
  bf16x8 ah[8], al[8];
  {
    const float* xr = x + (size_t)(nw + l15) * (GG * DD) + (size_t)g * DD + quad * 8;
#pragma unroll
    for (int ks = 0; ks < 8; ++ks) {
      float4 fa = *(const float4*)(xr + ks * 32);
      float4 fb = *(const float4*)(xr + ks * 32 + 4);
      float f[8] = {fa.x, fa.y, fa.z, fa.w, fb.x, fb.y, fb.z, fb.w};
#pragma unroll
      for (int j = 0; j < 8; ++j) {
        u16 h = f2bf(f[j]);
        ah[ks][j] = (short)h;
        al[ks][j] = (short)f2bf(f[j] - bf2f(h));
      }
    }
  }

  // per-lane per-row state (4 rows: r in 0..3; row = quad*4+r of this strip)
  float Zl[4], hv[4], z1[4], z2[4];
  int hid[4], i1[4], i2[4];
#pragma unroll
  for (int i = 0; i < 4; ++i) {
    Zl[i] = 0.f; hv[i] = -INFINITY; z1[i] = -INFINITY; z2[i] = -INFINITY;
    hid[i] = 0; i1[i] = 0; i2[i] = 0;
  }

#pragma unroll 1
  for (int t32 = 0; t32 < 32; ++t32) {
    __syncthreads();                     // stage(t32) landed; prev tile reads done
    if (t32 < 31) stage(t32 + 1, (t32 + 1) & 1);
    const u16* bh_p = &bt[t32 & 1][0];
    const u16* bl_p = &bt[t32 & 1][8192];
#pragma unroll 1
    for (int cg = 0; cg < 2; ++cg) {
      const int colG = t32 * 32 + cg * 16 + l15;
      float sqv = sq_e[g * MM + colG];
      float gv[4];
#pragma unroll
      for (int r = 0; r < 4; ++r)
        gv[r] = gum[((size_t)(nw + quad * 4 + r) * GG + g) * MM + colG];

      f32x4 c0 = {0,0,0,0}, c1 = {0,0,0,0}, c2 = {0,0,0,0};
#pragma unroll
      for (int ks = 0; ks < 8; ++ks) {
        int off = ((ks * 2 + cg) * 64 + lane) * 8;
        bf16x8 bh = *(const bf16x8*)(bh_p + off);
        bf16x8 bl = *(const bf16x8*)(bl_p + off);
        c0 = __builtin_amdgcn_mfma_f32_16x16x32_bf16(ah[ks], bh, c0, 0, 0, 0);
        c1 = __builtin_amdgcn_mfma_f32_16x16x32_bf16(ah[ks], bl, c1, 0, 0, 0);
        c2 = __builtin_amdgcn_mfma_f32_16x16x32_bf16(al[ks], bh, c2, 0, 0, 0);
      }
      ushort4 pk;
      u16* pp = (u16*)&pk;
#pragma unroll
      for (int r = 0; r < 4; ++r) {
        float lp = 2.f * (c0[r] + c1[r] + c2[r]) - sqv + SHIFT;
        float ev = __expf(fminf(lp, 80.f));
        Zl[r] += ev;
        pp[r] = f2bf(ev);
        if (lp > hv[r]) { hv[r] = lp; hid[r] = colG; }
        float zz = lp - __logf(neg_log_acc(gv[r]));
        if (zz > z1[r]) {
          z2[r] = z1[r]; i2[r] = i1[r];
          z1[r] = zz; i1[r] = colG;
        } else if (zz > z2[r]) {
          z2[r] = zz; i2[r] = colG;
        }
      }
      // est[g][m][n] bf16, 4 consecutive n per lane; per m, this block's 8
      // waves cover 256B contiguous n within one barrier epoch.
      *(ushort4*)&est[((size_t)(g * MM + colG) << 14) + nw + quad * 4] = pk;
    }
  }

  // ---- per-row finalize: reduce over the 16 l15 lanes of each quad ----
#pragma unroll 1
  for (int r = 0; r < 4; ++r) {
    const int row = wave * 16 + quad * 4 + r;
    const int n = n0 + row;
    float Zr = Zl[r], hvr = hv[r];
    int hir = hid[r];
    float v1 = z1[r], v2 = z2[r];
    int j1 = i1[r], j2 = i2[r];
#pragma unroll
    for (int o = 1; o <= 8; o <<= 1) {
      Zr += __shfl_xor(Zr, o);
      float ohv = __shfl_xor(hvr, o); int ohi = __shfl_xor(hir, o);
      if (ohv > hvr || (ohv == hvr && ohi < hir)) { hvr = ohv; hir = ohi; }
      float w1 = __shfl_xor(v1, o), w2 = __shfl_xor(v2, o);
      int k1 = __shfl_xor(j1, o), k2 = __shfl_xor(j2, o);
      if (w1 > v1 || (w1 == v1 && k1 < j1)) {
        if (v1 > w2 || (v1 == w2 && j1 < k2)) { v2 = v1; j2 = j1; }
        else { v2 = w2; j2 = k2; }
        v1 = w1; j1 = k1;
      } else if (w1 > v2 || (w1 == v2 && k1 < j2)) { v2 = w1; j2 = k1; }
    }
    int fidx = j1;
    if (v1 - v2 < REFINE_GAP) {
      // exact fp64 re-check, 16-lane parallel over d
      const float* xrow = x + (size_t)n * (GG * DD) + (size_t)g * DD;
      const float* eA = emb + ((size_t)g * MM + j1) * DD;
      const float* eB = emb + ((size_t)g * MM + j2) * DD;
      double dA = 0, sA = 0, dB = 0, sB = 0;
#pragma unroll
      for (int k = 0; k < 16; ++k) {
        int d = l15 * 16 + k;
        double xv = (double)xrow[d];
        double ea = (double)eA[d], eb = (double)eB[d];
        dA += xv * ea; sA += ea * ea;
        dB += xv * eb; sB += eb * eb;
      }
#pragma unroll
      for (int o = 1; o <= 8; o <<= 1) {
        dA += __shfl_xor(dA, o); sA += __shfl_xor(sA, o);
        dB += __shfl_xor(dB, o); sB += __shfl_xor(sB, o);
      }
      double uA = (double)gum[((size_t)n * GG + g) * MM + j1];
      double uB = (double)gum[((size_t)n * GG + g) * MM + j2];
      double zA = 2.0 * dA - sA - log(-log(uA));
      double zB = 2.0 * dB - sB - log(-log(uB));
      if (zB > zA || (zB == zA && j2 < j1)) fidx = j2;
    }
    if (l15 == 0) {
      out[OFF_I + (size_t)n * GG + g] = (float)fidx;
      atomicAdd(&hist[g * MM + hir], 1);
      invZ_ws[g * NTOT + n] = 1.f / Zr;
      fidx_lds[row] = fidx;
    }
  }
  __syncthreads();

  // ---- quantized rows + commitment-loss partial (coalesced) ----
  {
    float ls = 0.f;
#pragma unroll
    for (int j = 0; j < 16; ++j) {
      int idx = j * 512 + t;
      int row = idx >> 6, f4 = idx & 63;
      int n = n0 + row, fi = fidx_lds[row];
      float4 e4 = *(const float4*)&emb[((size_t)g * MM + fi) * DD + f4 * 4];
      float4 x4 = *(const float4*)&x[(size_t)n * (GG * DD) + (size_t)g * DD + f4 * 4];
      *(float4*)&out[OFF_Q + (size_t)n * (GG * DD) + (size_t)g * DD + f4 * 4] = e4;
      float dx = x4.x - e4.x, dy = x4.y - e4.y, dz = x4.z - e4.z, dw = x4.w - e4.w;
      ls += dx * dx + dy * dy + dz * dz + dw * dw;
    }
    ls = wave_sum_f(ls);
    if (lane == 0) atomicAdd(loss, (double)ls);
  }
}

// ---- avg_probs column reduction: avg[g][m] = sum_n est[g][m][n] * invZ[g][n]
__global__ void vq_avg(const u16* __restrict__ est, const float* __restrict__ invZ,
                       float* __restrict__ avg) {
  int wid = blockIdx.x * 4 + (threadIdx.x >> 6);   // 0..2047 = g*1024+m
  int lane = threadIdx.x & 63;
  const u16* base = est + ((size_t)wid << 14);
  const float* zp = invZ + ((wid >> 10) << 14);
  float acc = 0.f;
#pragma unroll 4
  for (int it = 0; it < 64; ++it) {
    int n = it * 256 + lane * 4;
    ushort4 e4 = *(const ushort4*)(base + n);
    float4 z4 = *(const float4*)(zp + n);
    acc += bf2f(e4.x) * z4.x + bf2f(e4.y) * z4.y +
           bf2f(e4.z) * z4.z + bf2f(e4.w) * z4.w;
  }
  acc = wave_sum_f(acc);
  if (lane == 0) avg[wid] = acc;
}

// ---- finalize: entropies + loss ----
__global__ void vq_fin(const float* __restrict__ avg, const int* __restrict__ hist,
                       const double* __restrict__ loss, float* __restrict__ out) {
  int g = blockIdx.x, t = threadIdx.x;
  float cp = 0.f, pp = 0.f;
  for (int m = t; m < MM; m += 256) {
    float hp = (float)hist[g * MM + m] * (1.f / 16384.f);
    cp += hp * log2f(hp + 1e-10f);
    float ap = avg[g * MM + m] * (1.f / 16384.f);
    pp += ap * log2f(ap + 1e-10f);
  }
  cp = wave_sum_f(cp);
  pp = wave_sum_f(pp);
  __shared__ float sc[4], sp[4];
  int wave = t >> 6, lane = t & 63;
  if (lane == 0) { sc[wave] = cp; sp[wave] = pp; }
  __syncthreads();
  if (t == 0) {
    out[OFF_CP + g] = -(sc[0] + sc[1] + sc[2] + sc[3]);
    out[OFF_PP + g] = -(sp[0] + sp[1] + sp[2] + sp[3]);
    if (g == 0) out[OFF_L] = (float)(*loss * (1.0 / 8388608.0));
  }
}

// ================= R2 fallback main (small ws) =================
__global__ __launch_bounds__(256, 3) void vq_main_fast(
    const float* __restrict__ x, const float* __restrict__ emb,
    const float* __restrict__ gum, const float* __restrict__ sq_e,
    const u16* __restrict__ eh, const u16* __restrict__ el,
    float* __restrict__ out, float* __restrict__ avg,
    int* __restrict__ hist, double* __restrict__ loss) {
  __shared__ u16 est_lds[4][16][264];
  __shared__ float colsum[MM];
  __shared__ float red[16][4][8];
  __shared__ float fin_invZ[16];
  __shared__ int fin_idx[16];

  const int g = blockIdx.y;
  const int n0 = blockIdx.x * 16;
  const int t = threadIdx.x;
  const int wave = t >> 6, lane = t & 63;
  const int quad = lane >> 4, l15 = lane & 15;
  const int wm0 = wave * 256;

  for (int i = t; i < MM; i += 256) colsum[i] = 0.f;

  bf16x8 ah[8], al[8];
  {
    const float* xr = x + (size_t)(n0 + l15) * (GG * DD) + (size_t)g * DD + quad * 8;
#pragma unroll
    for (int ks = 0; ks < 8; ++ks) {
      float4 fa = *(const float4*)(xr + ks * 32);
      float4 fb = *(const float4*)(xr + ks * 32 + 4);
      float f[8] = {fa.x, fa.y, fa.z, fa.w, fb.x, fb.y, fb.z, fb.w};
#pragma unroll
      for (int j = 0; j < 8; ++j) {
        u16 h = f2bf(f[j]);
        ah[ks][j] = (short)h;
        al[ks][j] = (short)f2bf(f[j] - bf2f(h));
      }
    }
  }
  const u16* ehb = eh + ((size_t)g * MM + wm0 + l15) * DD + quad * 8;
  const u16* elb = el + ((size_t)g * MM + wm0 + l15) * DD + quad * 8;
  const float* sqb = sq_e + g * MM + wm0 + l15;

  float Z[4] = {0.f, 0.f, 0.f, 0.f};
  float hv[4] = {-INFINITY, -INFINITY, -INFINITY, -INFINITY};
  int hid[4] = {0, 0, 0, 0};
  float z1[4] = {-INFINITY, -INFINITY, -INFINITY, -INFINITY};
  float z2[4] = {-INFINITY, -INFINITY, -INFINITY, -INFINITY};
  int i1[4] = {0, 0, 0, 0}, i2[4] = {0, 0, 0, 0};

#pragma unroll 2
  for (int tt = 0; tt < 16; ++tt) {
    float sqv = sqb[tt * 16];
    float gv[4];
#pragma unroll
    for (int r = 0; r < 4; ++r)
      gv[r] = gum[((size_t)(n0 + quad * 4 + r) * GG + g) * MM + wm0 + tt * 16 + l15];
    f32x4 a0 = {0,0,0,0}, a1 = {0,0,0,0}, a2 = {0,0,0,0};
#pragma unroll
    for (int ks = 0; ks < 8; ++ks) {
      bf16x8 bh = *(const bf16x8*)(ehb + (size_t)tt * 16 * DD + ks * 32);
      bf16x8 bl = *(const bf16x8*)(elb + (size_t)tt * 16 * DD + ks * 32);
      a0 = __builtin_amdgcn_mfma_f32_16x16x32_bf16(ah[ks], bh, a0, 0, 0, 0);
      a1 = __builtin_amdgcn_mfma_f32_16x16x32_bf16(ah[ks], bl, a1, 0, 0, 0);
      a2 = __builtin_amdgcn_mfma_f32_16x16x32_bf16(al[ks], bh, a2, 0, 0, 0);
    }
    const int colL = tt * 16 + l15;
    const int colG = wm0 + colL;
#pragma unroll
    for (int r = 0; r < 4; ++r) {
      float lp = 2.f * (a0[r] + a1[r] + a2[r]) - sqv + SHIFT;
      float ev = expf(fminf(lp, 80.f));
      Z[r] += ev;
      est_lds[wave][quad * 4 + r][colL] = f2bf(ev);
      if (lp > hv[r]) { hv[r] = lp; hid[r] = colG; }
      float zz = lp - logf(-logf(gv[r]));
      if (zz > z1[r]) { z2[r] = z1[r]; i2[r] = i1[r]; z1[r] = zz; i1[r] = colG; }
      else if (zz > z2[r]) { z2[r] = zz; i2[r] = colG; }
    }
  }
#pragma unroll
  for (int r = 0; r < 4; ++r) {
    float Zr = Z[r], hvr = hv[r];
    int hir = hid[r];
    float v1 = z1[r], v2 = z2[r];
    int j1 = i1[r], j2 = i2[r];
#pragma unroll
    for (int o = 1; o <= 8; o <<= 1) {
      Zr += __shfl_xor(Zr, o);
      float ohv = __shfl_xor(hvr, o); int ohi = __shfl_xor(hir, o);
      if (ohv > hvr || (ohv == hvr && ohi < hir)) { hvr = ohv; hir = ohi; }
      float w1 = __shfl_xor(v1, o), w2 = __shfl_xor(v2, o);
      int k1 = __shfl_xor(j1, o), k2 = __shfl_xor(j2, o);
      if (w1 > v1 || (w1 == v1 && k1 < j1)) {
        if (v1 > w2 || (v1 == w2 && j1 < k2)) { v2 = v1; j2 = j1; }
        else { v2 = w2; j2 = k2; }
        v1 = w1; j1 = k1;
      } else if (w1 > v2 || (w1 == v2 && k1 < j2)) { v2 = w1; j2 = k1; }
    }
    if (l15 == 0) {
      float* rp = red[quad * 4 + r][wave];
      rp[0] = Zr; rp[1] = hvr; rp[2] = __int_as_float(hir);
      rp[3] = v1; rp[4] = __int_as_float(j1);
      rp[5] = v2; rp[6] = __int_as_float(j2);
    }
  }
  __syncthreads();
  if (t < 16) {
    const int row = t, n = n0 + row;
    float Zf = 0.f, hvf = -INFINITY; int hif = 0;
    float v1 = -INFINITY, v2 = -INFINITY; int j1 = 0, j2 = 0;
    for (int w = 0; w < 4; ++w) {
      const float* rp = red[row][w];
      Zf += rp[0];
      float ohv = rp[1]; int ohi = __float_as_int(rp[2]);
      if (ohv > hvf || (ohv == hvf && ohi < hif)) { hvf = ohv; hif = ohi; }
      float w1 = rp[3], w2 = rp[5];
      int k1 = __float_as_int(rp[4]), k2 = __float_as_int(rp[6]);
      if (w1 > v1 || (w1 == v1 && k1 < j1)) {
        if (v1 > w2 || (v1 == w2 && j1 < k2)) { v2 = v1; j2 = j1; }
        else { v2 = w2; j2 = k2; }
        v1 = w1; j1 = k1;
      } else if (w1 > v2 || (w1 == v2 && k1 < j2)) { v2 = w1; j2 = k1; }
    }
    int fidx = j1;
    if (v1 - v2 < REFINE_GAP) {
      const float* xrow = x + (size_t)n * (GG * DD) + (size_t)g * DD;
      const float* eA = emb + ((size_t)g * MM + j1) * DD;
      const float* eB = emb + ((size_t)g * MM + j2) * DD;
      double dA = 0, sA = 0, dB = 0, sB = 0;
      for (int d = 0; d < DD; ++d) {
        double xv = xrow[d], ea = eA[d], eb = eB[d];
        dA += xv * ea; sA += ea * ea;
        dB += xv * eb; sB += eb * eb;
      }
      double uA = gum[((size_t)n * GG + g) * MM + j1];
      double uB = gum[((size_t)n * GG + g) * MM + j2];
      double zA = 2.0 * dA - sA - log(-log(uA));
      double zB = 2.0 * dB - sB - log(-log(uB));
      if (zB > zA || (zB == zA && j2 < j1)) fidx = j2;
    }
    out[OFF_I + (size_t)n * GG + g] = (float)fidx;
    atomicAdd(&hist[g * MM + hif], 1);
    fin_invZ[row] = 1.f / Zf;
    fin_idx[row] = fidx;
  }
  __syncthreads();
  {
    const int row = t >> 4, c = (t & 15) * 16;
    const int n = n0 + row, fidx = fin_idx[row];
    const float* er = emb + ((size_t)g * MM + fidx) * DD + c;
    const float* xq = x + (size_t)n * (GG * DD) + (size_t)g * DD + c;
    float* op = out + OFF_Q + (size_t)n * (GG * DD) + (size_t)g * DD + c;
    float ls = 0.f;
#pragma unroll
    for (int j = 0; j < 4; ++j) {
      float4 e4 = *(const float4*)(er + j * 4);
      float4 x4 = *(const float4*)(xq + j * 4);
      *(float4*)(op + j * 4) = e4;
      float dx = x4.x - e4.x, dy = x4.y - e4.y, dz = x4.z - e4.z, dw = x4.w - e4.w;
      ls += dx * dx + dy * dy + dz * dz + dw * dw;
    }
    ls = wave_sum_f(ls);
    if (lane == 0) atomicAdd(loss, (double)ls);
  }
  float iZ[4];
#pragma unroll
  for (int r = 0; r < 4; ++r) iZ[r] = fin_invZ[quad * 4 + r];
#pragma unroll 1
  for (int tt = 0; tt < 16; ++tt) {
    float v = 0.f;
#pragma unroll
    for (int r = 0; r < 4; ++r)
      v += bf2f(est_lds[wave][quad * 4 + r][tt * 16 + l15]) * iZ[r];
    v += __shfl_xor(v, 16);
    v += __shfl_xor(v, 32);
    if (lane < 16) colsum[wm0 + tt * 16 + lane] += v;
  }
  __syncthreads();
  for (int i = t; i < MM; i += 256) atomicAdd(&avg[g * MM + i], colsum[i]);
}

extern "C" void kernel_launch(void* const* d_in, const int* in_sizes, int n_in,
                              void* d_out, int out_size, void* d_ws, size_t ws_size,
                              hipStream_t stream) {
  const float* x = (const float*)d_in[0];
  const float* emb = (const float*)d_in[1];
  const float* gum = (const float*)d_in[2];
  float* out = (float*)d_out;

  float* sq_e = (float*)d_ws;
  float* avg = (float*)((char*)d_ws + 8192);
  int* hist = (int*)((char*)d_ws + 16384);
  double* loss = (double*)((char*)d_ws + 24576);

  if (ws_size >= WS_NEED3) {
    float* invZ = (float*)((char*)d_ws + WS_INVZ);
    u16* eh_sw = (u16*)((char*)d_ws + WS_EHSW);
    u16* el_sw = (u16*)((char*)d_ws + WS_ELSW);
    u16* est = (u16*)((char*)d_ws + WS_EST);
    vq_init2<<<512, 256, 0, stream>>>(emb, sq_e, avg, hist, loss, eh_sw, el_sw, 0);
    vq_init_swz<<<256, 256, 0, stream>>>(emb, eh_sw, el_sw);
    vq_main3<<<dim3(NTOT / 128, GG), 512, 0, stream>>>(
        x, emb, gum, sq_e, eh_sw, el_sw, out, est, invZ, hist, loss);
    vq_avg<<<512, 256, 0, stream>>>(est, invZ, avg);
    vq_fin<<<GG, 256, 0, stream>>>(avg, hist, loss, out);
  } else {
    // R2 fallback (needs 32KB + 2MB row-major hi/lo tables)
    u16* eh = (u16*)((char*)d_ws + 32768);
    u16* el = eh + (size_t)GG * MM * DD;
    vq_init2<<<512, 256, 0, stream>>>(emb, sq_e, avg, hist, loss, eh, el, 1);
    vq_main_fast<<<dim3(NTOT / 16, GG), 256, 0, stream>>>(
        x, emb, gum, sq_e, eh, el, out, avg, hist, loss);
    vq_fin<<<GG, 256, 0, stream>>>(avg, hist, loss, out);
  }
}

// Round 4
// 440.294 us; speedup vs baseline: 1.1085x; 1.1085x over previous
//
#include <hip/hip_runtime.h>
#include <math.h>

// Problem constants
#define NTOT 16384        // N = B*T
#define GG 2
#define MM 1024
#define DD 256

// Output layout (flat float32)
#define OFF_Q  ((size_t)0)
#define OFF_CP ((size_t)8388608)
#define OFF_PP ((size_t)8388610)
#define OFF_I  ((size_t)8388612)
#define OFF_L  ((size_t)8421380)

#define SHIFT 40.0f       // row-constant logit shift (softmax/argmax invariant)
#define REFINE_GAP 0.03f  // fp64 re-check threshold (fast-log z err << this)

typedef __attribute__((ext_vector_type(8))) short bf16x8;
typedef __attribute__((ext_vector_type(4))) float f32x4;
typedef unsigned short u16;
typedef unsigned int u32;

__device__ inline float wave_sum_f(float v) {
#pragma unroll
  for (int o = 32; o > 0; o >>= 1) v += __shfl_xor(v, o);
  return v;
}
__device__ inline u16 f2bf(float f) {
  u32 u = __float_as_uint(f);
  return (u16)((u + 0x7fffu + ((u >> 16) & 1u)) >> 16);
}
__device__ inline float bf2f(u16 h) {
  return __uint_as_float(((u32)h) << 16);
}
// async 16B global->LDS (LDS dest = wave-uniform base + lane*16)
__device__ inline void async16(const void* g, void* l) {
  __builtin_amdgcn_global_load_lds(
      (const __attribute__((address_space(1))) u32*)g,
      (__attribute__((address_space(3))) u32*)l, 16, 0, 0);
}
// -ln(u), accurate for u -> 1 (series) and u small (hw log).
__device__ inline float neg_log_acc(float u) {
  float t1 = 1.0f - u;
  float se = t1 * (1.f + t1 * (0.5f + t1 * (0.33333334f + t1 * 0.25f)));
  float fl = -__logf(u);
  return (t1 < 0.015625f) ? se : fl;
}

// ============ ws layout (v4) ============
// 0        sq_e f32[2048]
// 8192     avg  f32[2048]
// 16384    hist i32[2048]
// 24576    loss double
// 32768    invZ f32[2*16384]          (128KB)
// 163840   eh_sw u16[2*1024*256]      (1MB, MFMA-frag swizzled)
// 1212416  el_sw u16[2*1024*256]      (1MB)
// 2260992  est  u16[2*1024*16384]     (64MB, [g][m][n] bf16)
// 69369856 part f32[2g][2mh][16384][8] (2MB per-row partials)
#define WS_INVZ   32768
#define WS_EHSW   163840
#define WS_ELSW   1212416
#define WS_EST    2260992
#define WS_PART   69369856ull
#define WS_NEED4  (WS_PART + 4ull * GG * 2 * NTOT * 8)

// ---- init A: sq_e + zero hist/loss (+ optional row-major hi/lo for fallback)
__global__ void vq_init2(const float* __restrict__ emb, float* __restrict__ sq_e,
                         float* __restrict__ avg, int* __restrict__ hist,
                         double* __restrict__ loss, u16* __restrict__ eh,
                         u16* __restrict__ el, int do_split) {
  const int row = blockIdx.x * 4 + (threadIdx.x >> 6);
  const int lane = threadIdx.x & 63;
  float4 e4 = *(const float4*)&emb[(size_t)row * DD + lane * 4];
  float s = e4.x * e4.x + e4.y * e4.y + e4.z * e4.z + e4.w * e4.w;
  s = wave_sum_f(s);
  if (do_split) {
    ushort4 h, l;
    h.x = f2bf(e4.x); l.x = f2bf(e4.x - bf2f(h.x));
    h.y = f2bf(e4.y); l.y = f2bf(e4.y - bf2f(h.y));
    h.z = f2bf(e4.z); l.z = f2bf(e4.z - bf2f(h.z));
    h.w = f2bf(e4.w); l.w = f2bf(e4.w - bf2f(h.w));
    *(ushort4*)&eh[(size_t)row * DD + lane * 4] = h;
    *(ushort4*)&el[(size_t)row * DD + lane * 4] = l;
  }
  if (lane == 0) sq_e[row] = s;
  if (blockIdx.x == 0) {
    for (int i = threadIdx.x; i < GG * MM; i += 256) { avg[i] = 0.f; hist[i] = 0; }
    if (threadIdx.x == 0) *loss = 0.0;
  }
}

// ---- init B: build swizzled hi/lo tables in MFMA-frag chunk order.
// chunk(g,ct,ks,cg,quad,l15) = B[col=ct*64+cg*16+l15][k=ks*32+quad*8 .. +8]
// linear chunk idx = (((g*16+ct)*8+ks)*4+cg)*64 + quad*16 + l15, 16B each.
__global__ void vq_init_swz(const float* __restrict__ emb, u16* __restrict__ eh_sw,
                            u16* __restrict__ el_sw) {
  int tid = blockIdx.x * 256 + threadIdx.x;   // 0..65535
  int g = tid >> 15, rem = tid & 32767;
  int col = rem >> 5, kc = rem & 31;          // kc: 8-element k-chunk
  const float* src = emb + ((size_t)(g * MM + col)) * DD + kc * 8;
  float4 fa = *(const float4*)src;
  float4 fb = *(const float4*)(src + 4);
  float f[8] = {fa.x, fa.y, fa.z, fa.w, fb.x, fb.y, fb.z, fb.w};
  u16 hi[8], lo[8];
#pragma unroll
  for (int j = 0; j < 8; ++j) {
    hi[j] = f2bf(f[j]);
    lo[j] = f2bf(f[j] - bf2f(hi[j]));
  }
  int ct = col >> 6, cg = (col >> 4) & 3, l15 = col & 15;
  int ks = kc >> 2, quad = kc & 3;
  size_t chunk = ((((size_t)g * 16 + ct) * 8 + ks) * 4 + cg) * 64 + quad * 16 + l15;
  ushort4* dh = (ushort4*)(eh_sw + chunk * 8);
  ushort4* dl = (ushort4*)(el_sw + chunk * 8);
  dh[0] = make_ushort4(hi[0], hi[1], hi[2], hi[3]);
  dh[1] = make_ushort4(hi[4], hi[5], hi[6], hi[7]);
  dl[0] = make_ushort4(lo[0], lo[1], lo[2], lo[3]);
  dl[1] = make_ushort4(lo[4], lo[5], lo[6], lo[7]);
}

// ---- main v7: grid (128 nb, 2 g, 2 mh) = 512 blocks; 512 thr = 8 waves x
// 16 rows; each block sweeps 512 m (its half) over 16 x 32-col double-buffered
// tiles (64KB LDS -> 2 blocks/CU, 16 waves/CU). est per (m,block) = 256B
// contiguous (clean sectors). Per-row partials go to ws; cross-half merge +
// refine + quantize live in vq_merge.
__global__ __launch_bounds__(512, 4) void vq_main4(
    const float* __restrict__ x, const float* __restrict__ gum,
    const float* __restrict__ sq_e, const u16* __restrict__ eh_sw,
    const u16* __restrict__ el_sw, u16* __restrict__ est,
    float* __restrict__ part) {
  __shared__ u16 bt[2][16384];     // 2 x 32KB tile buffers

  const int g = blockIdx.y, mh = blockIdx.z;
  const int n0 = blockIdx.x * 128;
  const int t = threadIdx.x;
  const int wave = t >> 6, lane = t & 63;
  const int quad = lane >> 4, l15 = lane & 15;
  const int nw = n0 + wave * 16;   // this wave's first row
  const int m0 = mh * 512;

  const u16* sgh = eh_sw + (size_t)g * 16 * 16384;  // 16 chunks x 16384 u16
  const u16* sgl = el_sw + (size_t)g * 16 * 16384;

  // local tile t32 (0..15) = 32 cols: ct = mh*8 + (t32>>1), cg pair (t32&1)*2
  auto stage = [&](int t32, int buf) {
    int ct = mh * 8 + (t32 >> 1), pb = (t32 & 1) * 2;
    const u16* sh = sgh + (size_t)ct * 16384;
    const u16* sl = sgl + (size_t)ct * 16384;
    u16* dh = &bt[buf][0];
    u16* dl = &bt[buf][8192];
#pragma unroll
    for (int j = 0; j < 2; ++j) {
      int slot = j * 8 + wave;            // 0..15
      int ks = slot >> 1, cgp = slot & 1;
      int so = (ks * 4 + pb + cgp) * 512;
      async16(sh + so + lane * 8, dh + slot * 512);
      async16(sl + so + lane * 8, dl + slot * 512);
    }
  };

  stage(0, 0);   // overlap with A-frag global loads below

  // ---- build A fragments from global (16 rows, 8 k-steps, hi+lo split) ----
  bf16x8 ah[8], al[8];
  {
    const float* xr = x + (size_t)(nw + l15) * (GG * DD) + (size_t)g * DD + quad * 8;
#pragma unroll
    for (int ks = 0; ks < 8; ++ks) {
      float4 fa = *(const float4*)(xr + ks * 32);
      float4 fb = *(const float4*)(xr + ks * 32 + 4);
      float f[8] = {fa.x, fa.y, fa.z, fa.w, fb.x, fb.y, fb.z, fb.w};
#pragma unroll
      for (int j = 0; j < 8; ++j) {
        u16 h = f2bf(f[j]);
        ah[ks][j] = (short)h;
        al[ks][j] = (short)f2bf(f[j] - bf2f(h));
      }
    }
  }

  // per-lane per-row state (4 rows: r in 0..3; row = quad*4+r of this strip)
  float Zl[4], hv[4], z1[4], z2[4];
  int hid[4], i1[4], i2[4];
#pragma unroll
  for (int i = 0; i < 4; ++i) {
    Zl[i] = 0.f; hv[i] = -INFINITY; z1[i] = -INFINITY; z2[i] = -INFINITY;
    hid[i] = 0; i1[i] = 0; i2[i] = 0;
  }

#pragma unroll 1
  for (int t32 = 0; t32 < 16; ++t32) {
    __syncthreads();                     // stage(t32) landed; prev tile reads done
    if (t32 < 15) stage(t32 + 1, (t32 + 1) & 1);
    const u16* bh_p = &bt[t32 & 1][0];
    const u16* bl_p = &bt[t32 & 1][8192];
#pragma unroll 1
    for (int cg = 0; cg < 2; ++cg) {
      const int colG = m0 + t32 * 32 + cg * 16 + l15;
      float sqv = sq_e[g * MM + colG];
      float gv[4];
#pragma unroll
      for (int r = 0; r < 4; ++r)
        gv[r] = gum[((size_t)(nw + quad * 4 + r) * GG + g) * MM + colG];

      f32x4 c0 = {0,0,0,0}, c1 = {0,0,0,0}, c2 = {0,0,0,0};
#pragma unroll
      for (int ks = 0; ks < 8; ++ks) {
        int off = ((ks * 2 + cg) * 64 + lane) * 8;
        bf16x8 bh = *(const bf16x8*)(bh_p + off);
        bf16x8 bl = *(const bf16x8*)(bl_p + off);
        c0 = __builtin_amdgcn_mfma_f32_16x16x32_bf16(ah[ks], bh, c0, 0, 0, 0);
        c1 = __builtin_amdgcn_mfma_f32_16x16x32_bf16(ah[ks], bl, c1, 0, 0, 0);
        c2 = __builtin_amdgcn_mfma_f32_16x16x32_bf16(al[ks], bh, c2, 0, 0, 0);
      }
      ushort4 pk;
      u16* pp = (u16*)&pk;
#pragma unroll
      for (int r = 0; r < 4; ++r) {
        float lp = 2.f * (c0[r] + c1[r] + c2[r]) - sqv + SHIFT;
        float ev = __expf(fminf(lp, 80.f));
        Zl[r] += ev;
        pp[r] = f2bf(ev);
        if (lp > hv[r]) { hv[r] = lp; hid[r] = colG; }
        float zz = lp - __logf(neg_log_acc(gv[r]));
        if (zz > z1[r]) {
          z2[r] = z1[r]; i2[r] = i1[r];
          z1[r] = zz; i1[r] = colG;
        } else if (zz > z2[r]) {
          z2[r] = zz; i2[r] = colG;
        }
      }
      // est[g][m][n] bf16; per m this block's 8 waves cover 256B contiguous n
      *(ushort4*)&est[((size_t)(g * MM + colG) << 14) + nw + quad * 4] = pk;
    }
  }

  // ---- per-row 16-lane reduce; write per-half partials to ws ----
#pragma unroll 1
  for (int r = 0; r < 4; ++r) {
    float Zr = Zl[r], hvr = hv[r];
    int hir = hid[r];
    float v1 = z1[r], v2 = z2[r];
    int j1 = i1[r], j2 = i2[r];
#pragma unroll
    for (int o = 1; o <= 8; o <<= 1) {
      Zr += __shfl_xor(Zr, o);
      float ohv = __shfl_xor(hvr, o); int ohi = __shfl_xor(hir, o);
      if (ohv > hvr || (ohv == hvr && ohi < hir)) { hvr = ohv; hir = ohi; }
      float w1 = __shfl_xor(v1, o), w2 = __shfl_xor(v2, o);
      int k1 = __shfl_xor(j1, o), k2 = __shfl_xor(j2, o);
      if (w1 > v1 || (w1 == v1 && k1 < j1)) {
        if (v1 > w2 || (v1 == w2 && j1 < k2)) { v2 = v1; j2 = j1; }
        else { v2 = w2; j2 = k2; }
        v1 = w1; j1 = k1;
      } else if (w1 > v2 || (w1 == v2 && k1 < j2)) { v2 = w1; j2 = k1; }
    }
    if (l15 == 0) {
      const int n = nw + quad * 4 + r;
      float* rp = part + ((size_t)(g * 2 + mh) * NTOT + n) * 8;
      *(float4*)rp = make_float4(Zr, hvr, __int_as_float(hir), v1);
      *(float4*)(rp + 4) =
          make_float4(__int_as_float(j1), v2, __int_as_float(j2), 0.f);
    }
  }
}

// ---- merge halves + refine + out_I/hist/invZ + quantize rows + loss ----
__global__ __launch_bounds__(256, 4) void vq_merge(
    const float* __restrict__ x, const float* __restrict__ emb,
    const float* __restrict__ gum, const float* __restrict__ part,
    float* __restrict__ out, float* __restrict__ invZ_ws,
    int* __restrict__ hist, double* __restrict__ loss) {
  __shared__ int fidx_lds[128];
  const int g = blockIdx.y;
  const int n0 = blockIdx.x * 128;
  const int t = threadIdx.x;
  const int lane = t & 63;

  if (t < 128) {       // waves 0,1 fully active
    const int n = n0 + t;
    const float* pa = part + ((size_t)(g * 2 + 0) * NTOT + n) * 8;
    const float* pb = part + ((size_t)(g * 2 + 1) * NTOT + n) * 8;
    float4 a0 = *(const float4*)pa, a1 = *(const float4*)(pa + 4);
    float4 b0 = *(const float4*)pb, b1 = *(const float4*)(pb + 4);
    float Z = a0.x + b0.x;
    float hv = a0.y; int hid = __float_as_int(a0.z);
    if (b0.y > hv) { hv = b0.y; hid = __float_as_int(b0.z); }  // tie: half0 wins
    float v1 = a0.w, v2 = a1.y;
    int j1 = __float_as_int(a1.x), j2 = __float_as_int(a1.z);
    {
      float w1 = b0.w, w2 = b1.y;
      int k1 = __float_as_int(b1.x), k2 = __float_as_int(b1.z);
      // all half1 indices > half0 indices -> strict > keeps half0 on ties
      if (w1 > v1) {
        if (v1 > w2 || (v1 == w2 && j1 < k2)) { v2 = v1; j2 = j1; }
        else { v2 = w2; j2 = k2; }
        v1 = w1; j1 = k1;
      } else if (w1 > v2 || (w1 == v2 && k1 < j2)) { v2 = w1; j2 = k1; }
    }
    int fidx = j1;
    int need = (v1 - v2 < REFINE_GAP) ? 1 : 0;

    // wave-cooperative exact fp64 re-check for flagged rows
    unsigned long long mask = __ballot(need);
    while (mask) {
      int src = (int)(__ffsll(mask) - 1);
      int nn = __shfl(n, src);
      int ja = __shfl(j1, src), jb = __shfl(j2, src);
      const float* xrow = x + (size_t)nn * (GG * DD) + (size_t)g * DD;
      const float* eA = emb + ((size_t)g * MM + ja) * DD;
      const float* eB = emb + ((size_t)g * MM + jb) * DD;
      int d = lane * 4;
      float4 xv4 = *(const float4*)&xrow[d];
      float4 ea4 = *(const float4*)&eA[d];
      float4 eb4 = *(const float4*)&eB[d];
      double dA = 0, sA = 0, dB = 0, sB = 0;
      {
        double xv = xv4.x, ea = ea4.x, eb = eb4.x;
        dA += xv * ea; sA += ea * ea; dB += xv * eb; sB += eb * eb;
        xv = xv4.y; ea = ea4.y; eb = eb4.y;
        dA += xv * ea; sA += ea * ea; dB += xv * eb; sB += eb * eb;
        xv = xv4.z; ea = ea4.z; eb = eb4.z;
        dA += xv * ea; sA += ea * ea; dB += xv * eb; sB += eb * eb;
        xv = xv4.w; ea = ea4.w; eb = eb4.w;
        dA += xv * ea; sA += ea * ea; dB += xv * eb; sB += eb * eb;
      }
#pragma unroll
      for (int o = 1; o <= 32; o <<= 1) {
        dA += __shfl_xor(dA, o); sA += __shfl_xor(sA, o);
        dB += __shfl_xor(dB, o); sB += __shfl_xor(sB, o);
      }
      double uA = (double)gum[((size_t)nn * GG + g) * MM + ja];
      double uB = (double)gum[((size_t)nn * GG + g) * MM + jb];
      double zA = 2.0 * dA - sA - log(-log(uA));
      double zB = 2.0 * dB - sB - log(-log(uB));
      if (lane == src && (zB > zA || (zB == zA && jb < ja))) fidx = jb;
      mask &= mask - 1;
    }

    out[OFF_I + (size_t)n * GG + g] = (float)fidx;
    atomicAdd(&hist[g * MM + hid], 1);
    invZ_ws[g * NTOT + n] = 1.f / Z;
    fidx_lds[t] = fidx;
  }
  __syncthreads();

  // ---- quantized rows + commitment-loss partial (coalesced) ----
  {
    float ls = 0.f;
#pragma unroll
    for (int j = 0; j < 32; ++j) {
      int idx = j * 256 + t;
      int row = idx >> 6, f4 = idx & 63;
      int n = n0 + row, fi = fidx_lds[row];
      float4 e4 = *(const float4*)&emb[((size_t)g * MM + fi) * DD + f4 * 4];
      float4 x4 = *(const float4*)&x[(size_t)n * (GG * DD) + (size_t)g * DD + f4 * 4];
      *(float4*)&out[OFF_Q + (size_t)n * (GG * DD) + (size_t)g * DD + f4 * 4] = e4;
      float dx = x4.x - e4.x, dy = x4.y - e4.y, dz = x4.z - e4.z, dw = x4.w - e4.w;
      ls += dx * dx + dy * dy + dz * dz + dw * dw;
    }
    ls = wave_sum_f(ls);
    if (lane == 0) atomicAdd(loss, (double)ls);
  }
}

// ---- avg_probs column reduction: avg[g][m] = sum_n est[g][m][n] * invZ[g][n]
// one block per (g,m) row; 2048 blocks x 256 thr (32 waves/CU when packed)
__global__ void vq_avg(const u16* __restrict__ est, const float* __restrict__ invZ,
                       float* __restrict__ avg) {
  int wid = blockIdx.x;                // 0..2047 = g*1024+m
  int t = threadIdx.x;
  const u16* base = est + ((size_t)wid << 14);
  const float* zp = invZ + ((wid >> 10) << 14);
  float acc = 0.f;
#pragma unroll
  for (int it = 0; it < 8; ++it) {
    int n = it * 2048 + t * 8;
    uint4 e = *(const uint4*)(base + n);   // 8 bf16
    float4 z0 = *(const float4*)(zp + n);
    float4 z1 = *(const float4*)(zp + n + 4);
    acc += bf2f((u16)(e.x & 0xffff)) * z0.x + bf2f((u16)(e.x >> 16)) * z0.y +
           bf2f((u16)(e.y & 0xffff)) * z0.z + bf2f((u16)(e.y >> 16)) * z0.w +
           bf2f((u16)(e.z & 0xffff)) * z1.x + bf2f((u16)(e.z >> 16)) * z1.y +
           bf2f((u16)(e.w & 0xffff)) * z1.z + bf2f((u16)(e.w >> 16)) * z1.w;
  }
  acc = wave_sum_f(acc);
  __shared__ float sw[4];
  if ((t & 63) == 0) sw[t >> 6] = acc;
  __syncthreads();
  if (t == 0) avg[wid] = sw[0] + sw[1] + sw[2] + sw[3];
}

// ---- finalize: entropies + loss ----
__global__ void vq_fin(const float* __restrict__ avg, const int* __restrict__ hist,
                       const double* __restrict__ loss, float* __restrict__ out) {
  int g = blockIdx.x, t = threadIdx.x;
  float cp = 0.f, pp = 0.f;
  for (int m = t; m < MM; m += 256) {
    float hp = (float)hist[g * MM + m] * (1.f / 16384.f);
    cp += hp * log2f(hp + 1e-10f);
    float ap = avg[g * MM + m] * (1.f / 16384.f);
    pp += ap * log2f(ap + 1e-10f);
  }
  cp = wave_sum_f(cp);
  pp = wave_sum_f(pp);
  __shared__ float sc[4], sp[4];
  int wave = t >> 6, lane = t & 63;
  if (lane == 0) { sc[wave] = cp; sp[wave] = pp; }
  __syncthreads();
  if (t == 0) {
    out[OFF_CP + g] = -(sc[0] + sc[1] + sc[2] + sc[3]);
    out[OFF_PP + g] = -(sp[0] + sp[1] + sp[2] + sp[3]);
    if (g == 0) out[OFF_L] = (float)(*loss * (1.0 / 8388608.0));
  }
}

// ================= fallback main (small ws) =================
__global__ __launch_bounds__(256, 3) void vq_main_fast(
    const float* __restrict__ x, const float* __restrict__ emb,
    const float* __restrict__ gum, const float* __restrict__ sq_e,
    const u16* __restrict__ eh, const u16* __restrict__ el,
    float* __restrict__ out, float* __restrict__ avg,
    int* __restrict__ hist, double* __restrict__ loss) {
  __shared__ u16 est_lds[4][16][264];
  __shared__ float colsum[MM];
  __shared__ float red[16][4][8];
  __shared__ float fin_invZ[16];
  __shared__ int fin_idx[16];

  const int g = blockIdx.y;
  const int n0 = blockIdx.x * 16;
  const int t = threadIdx.x;
  const int wave = t >> 6, lane = t & 63;
  const int quad = lane >> 4, l15 = lane & 15;
  const int wm0 = wave * 256;

  for (int i = t; i < MM; i += 256) colsum[i] = 0.f;

  bf16x8 ah[8], al[8];
  {
    const float* xr = x + (size_t)(n0 + l15) * (GG * DD) + (size_t)g * DD + quad * 8;
#pragma unroll
    for (int ks = 0; ks < 8; ++ks) {
      float4 fa = *(const float4*)(xr + ks * 32);
      float4 fb = *(const float4*)(xr + ks * 32 + 4);
      float f[8] = {fa.x, fa.y, fa.z, fa.w, fb.x, fb.y, fb.z, fb.w};
#pragma unroll
      for (int j = 0; j < 8; ++j) {
        u16 h = f2bf(f[j]);
        ah[ks][j] = (short)h;
        al[ks][j] = (short)f2bf(f[j] - bf2f(h));
      }
    }
  }
  const u16* ehb = eh + ((size_t)g * MM + wm0 + l15) * DD + quad * 8;
  const u16* elb = el + ((size_t)g * MM + wm0 + l15) * DD + quad * 8;
  const float* sqb = sq_e + g * MM + wm0 + l15;

  float Z[4] = {0.f, 0.f, 0.f, 0.f};
  float hv[4] = {-INFINITY, -INFINITY, -INFINITY, -INFINITY};
  int hid[4] = {0, 0, 0, 0};
  float z1[4] = {-INFINITY, -INFINITY, -INFINITY, -INFINITY};
  float z2[4] = {-INFINITY, -INFINITY, -INFINITY, -INFINITY};
  int i1[4] = {0, 0, 0, 0}, i2[4] = {0, 0, 0, 0};

#pragma unroll 2
  for (int tt = 0; tt < 16; ++tt) {
    float sqv = sqb[tt * 16];
    float gv[4];
#pragma unroll
    for (int r = 0; r < 4; ++r)
      gv[r] = gum[((size_t)(n0 + quad * 4 + r) * GG + g) * MM + wm0 + tt * 16 + l15];
    f32x4 a0 = {0,0,0,0}, a1 = {0,0,0,0}, a2 = {0,0,0,0};
#pragma unroll
    for (int ks = 0; ks < 8; ++ks) {
      bf16x8 bh = *(const bf16x8*)(ehb + (size_t)tt * 16 * DD + ks * 32);
      bf16x8 bl = *(const bf16x8*)(elb + (size_t)tt * 16 * DD + ks * 32);
      a0 = __builtin_amdgcn_mfma_f32_16x16x32_bf16(ah[ks], bh, a0, 0, 0, 0);
      a1 = __builtin_amdgcn_mfma_f32_16x16x32_bf16(ah[ks], bl, a1, 0, 0, 0);
      a2 = __builtin_amdgcn_mfma_f32_16x16x32_bf16(al[ks], bh, a2, 0, 0, 0);
    }
    const int colL = tt * 16 + l15;
    const int colG = wm0 + colL;
#pragma unroll
    for (int r = 0; r < 4; ++r) {
      float lp = 2.f * (a0[r] + a1[r] + a2[r]) - sqv + SHIFT;
      float ev = expf(fminf(lp, 80.f));
      Z[r] += ev;
      est_lds[wave][quad * 4 + r][colL] = f2bf(ev);
      if (lp > hv[r]) { hv[r] = lp; hid[r] = colG; }
      float zz = lp - logf(-logf(gv[r]));
      if (zz > z1[r]) { z2[r] = z1[r]; i2[r] = i1[r]; z1[r] = zz; i1[r] = colG; }
      else if (zz > z2[r]) { z2[r] = zz; i2[r] = colG; }
    }
  }
#pragma unroll
  for (int r = 0; r < 4; ++r) {
    float Zr = Z[r], hvr = hv[r];
    int hir = hid[r];
    float v1 = z1[r], v2 = z2[r];
    int j1 = i1[r], j2 = i2[r];
#pragma unroll
    for (int o = 1; o <= 8; o <<= 1) {
      Zr += __shfl_xor(Zr, o);
      float ohv = __shfl_xor(hvr, o); int ohi = __shfl_xor(hir, o);
      if (ohv > hvr || (ohv == hvr && ohi < hir)) { hvr = ohv; hir = ohi; }
      float w1 = __shfl_xor(v1, o), w2 = __shfl_xor(v2, o);
      int k1 = __shfl_xor(j1, o), k2 = __shfl_xor(j2, o);
      if (w1 > v1 || (w1 == v1 && k1 < j1)) {
        if (v1 > w2 || (v1 == w2 && j1 < k2)) { v2 = v1; j2 = j1; }
        else { v2 = w2; j2 = k2; }
        v1 = w1; j1 = k1;
      } else if (w1 > v2 || (w1 == v2 && k1 < j2)) { v2 = w1; j2 = k1; }
    }
    if (l15 == 0) {
      float* rp = red[quad * 4 + r][wave];
      rp[0] = Zr; rp[1] = hvr; rp[2] = __int_as_float(hir);
      rp[3] = v1; rp[4] = __int_as_float(j1);
      rp[5] = v2; rp[6] = __int_as_float(j2);
    }
  }
  __syncthreads();
  if (t < 16) {
    const int row = t, n = n0 + row;
    float Zf = 0.f, hvf = -INFINITY; int hif = 0;
    float v1 = -INFINITY, v2 = -INFINITY; int j1 = 0, j2 = 0;
    for (int w = 0; w < 4; ++w) {
      const float* rp = red[row][w];
      Zf += rp[0];
      float ohv = rp[1]; int ohi = __float_as_int(rp[2]);
      if (ohv > hvf || (ohv == hvf && ohi < hif)) { hvf = ohv; hif = ohi; }
      float w1 = rp[3], w2 = rp[5];
      int k1 = __float_as_int(rp[4]), k2 = __float_as_int(rp[6]);
      if (w1 > v1 || (w1 == v1 && k1 < j1)) {
        if (v1 > w2 || (v1 == w2 && j1 < k2)) { v2 = v1; j2 = j1; }
        else { v2 = w2; j2 = k2; }
        v1 = w1; j1 = k1;
      } else if (w1 > v2 || (w1 == v2 && k1 < j2)) { v2 = w1; j2 = k1; }
    }
    int fidx = j1;
    if (v1 - v2 < REFINE_GAP) {
      const float* xrow = x + (size_t)n * (GG * DD) + (size_t)g * DD;
      const float* eA = emb + ((size_t)g * MM + j1) * DD;
      const float* eB = emb + ((size_t)g * MM + j2) * DD;
      double dA = 0, sA = 0, dB = 0, sB = 0;
      for (int d = 0; d < DD; ++d) {
        double xv = xrow[d], ea = eA[d], eb = eB[d];
        dA += xv * ea; sA += ea * ea;
        dB += xv * eb; sB += eb * eb;
      }
      double uA = gum[((size_t)n * GG + g) * MM + j1];
      double uB = gum[((size_t)n * GG + g) * MM + j2];
      double zA = 2.0 * dA - sA - log(-log(uA));
      double zB = 2.0 * dB - sB - log(-log(uB));
      if (zB > zA || (zB == zA && j2 < j1)) fidx = j2;
    }
    out[OFF_I + (size_t)n * GG + g] = (float)fidx;
    atomicAdd(&hist[g * MM + hif], 1);
    fin_invZ[row] = 1.f / Zf;
    fin_idx[row] = fidx;
  }
  __syncthreads();
  {
    const int row = t >> 4, c = (t & 15) * 16;
    const int n = n0 + row, fidx = fin_idx[row];
    const float* er = emb + ((size_t)g * MM + fidx) * DD + c;
    const float* xq = x + (size_t)n * (GG * DD) + (size_t)g * DD + c;
    float* op = out + OFF_Q + (size_t)n * (GG * DD) + (size_t)g * DD + c;
    float ls = 0.f;
#pragma unroll
    for (int j = 0; j < 4; ++j) {
      float4 e4 = *(const float4*)(er + j * 4);
      float4 x4 = *(const float4*)(xq + j * 4);
      *(float4*)(op + j * 4) = e4;
      float dx = x4.x - e4.x, dy = x4.y - e4.y, dz = x4.z - e4.z, dw = x4.w - e4.w;
      ls += dx * dx + dy * dy + dz * dz + dw * dw;
    }
    ls = wave_sum_f(ls);
    if (lane == 0) atomicAdd(loss, (double)ls);
  }
  float iZ[4];
#pragma unroll
  for (int r = 0; r < 4; ++r) iZ[r] = fin_invZ[quad * 4 + r];
#pragma unroll 1
  for (int tt = 0; tt < 16; ++tt) {
    float v = 0.f;
#pragma unroll
    for (int r = 0; r < 4; ++r)
      v += bf2f(est_lds[wave][quad * 4 + r][tt * 16 + l15]) * iZ[r];
    v += __shfl_xor(v, 16);
    v += __shfl_xor(v, 32);
    if (lane < 16) colsum[wm0 + tt * 16 + lane] += v;
  }
  __syncthreads();
  for (int i = t; i < MM; i += 256) atomicAdd(&avg[g * MM + i], colsum[i]);
}

extern "C" void kernel_launch(void* const* d_in, const int* in_sizes, int n_in,
                              void* d_out, int out_size, void* d_ws, size_t ws_size,
                              hipStream_t stream) {
  const float* x = (const float*)d_in[0];
  const float* emb = (const float*)d_in[1];
  const float* gum = (const float*)d_in[2];
  float* out = (float*)d_out;

  float* sq_e = (float*)d_ws;
  float* avg = (float*)((char*)d_ws + 8192);
  int* hist = (int*)((char*)d_ws + 16384);
  double* loss = (double*)((char*)d_ws + 24576);

  if (ws_size >= WS_NEED4) {
    float* invZ = (float*)((char*)d_ws + WS_INVZ);
    u16* eh_sw = (u16*)((char*)d_ws + WS_EHSW);
    u16* el_sw = (u16*)((char*)d_ws + WS_ELSW);
    u16* est = (u16*)((char*)d_ws + WS_EST);
    float* part = (float*)((char*)d_ws + WS_PART);
    vq_init2<<<512, 256, 0, stream>>>(emb, sq_e, avg, hist, loss, eh_sw, el_sw, 0);
    vq_init_swz<<<256, 256, 0, stream>>>(emb, eh_sw, el_sw);
    vq_main4<<<dim3(NTOT / 128, GG, 2), 512, 0, stream>>>(
        x, gum, sq_e, eh_sw, el_sw, est, part);
    vq_merge<<<dim3(NTOT / 128, GG), 256, 0, stream>>>(
        x, emb, gum, part, out, invZ, hist, loss);
    vq_avg<<<2048, 256, 0, stream>>>(est, invZ, avg);
    vq_fin<<<GG, 256, 0, stream>>>(avg, hist, loss, out);
  } else {
    // fallback (needs 32KB + 2MB row-major hi/lo tables)
    u16* eh = (u16*)((char*)d_ws + 32768);
    u16* el = eh + (size_t)GG * MM * DD;
    vq_init2<<<512, 256, 0, stream>>>(emb, sq_e, avg, hist, loss, eh, el, 1);
    vq_main_fast<<<dim3(NTOT / 16, GG), 256, 0, stream>>>(
        x, emb, gum, sq_e, eh, el, out, avg, hist, loss);
    vq_fin<<<GG, 256, 0, stream>>>(avg, hist, loss, out);
  }
}

// Round 5
// 359.436 us; speedup vs baseline: 1.3578x; 1.2250x over previous
//
#include <hip/hip_runtime.h>
#include <math.h>

// Problem constants
#define NTOT 16384        // N = B*T
#define GG 2
#define MM 1024
#define DD 256

// Output layout (flat float32)
#define OFF_Q  ((size_t)0)
#define OFF_CP ((size_t)8388608)
#define OFF_PP ((size_t)8388610)
#define OFF_I  ((size_t)8388612)
#define OFF_L  ((size_t)8421380)

#define SHIFT 40.0f       // row-constant logit shift (softmax/argmax invariant)
#define REFINE_GAP 0.03f  // fp64 re-check threshold (fast-log z err << this)

typedef __attribute__((ext_vector_type(8))) short bf16x8;
typedef __attribute__((ext_vector_type(4))) float f32x4;
typedef unsigned short u16;
typedef unsigned int u32;

__device__ inline float wave_sum_f(float v) {
#pragma unroll
  for (int o = 32; o > 0; o >>= 1) v += __shfl_xor(v, o);
  return v;
}
__device__ inline u16 f2bf(float f) {
  u32 u = __float_as_uint(f);
  return (u16)((u + 0x7fffu + ((u >> 16) & 1u)) >> 16);
}
__device__ inline float bf2f(u16 h) {
  return __uint_as_float(((u32)h) << 16);
}
// async 16B global->LDS (LDS dest = wave-uniform base + lane*16)
__device__ inline void async16(const void* g, void* l) {
  __builtin_amdgcn_global_load_lds(
      (const __attribute__((address_space(1))) u32*)g,
      (__attribute__((address_space(3))) u32*)l, 16, 0, 0);
}
// -ln(u), accurate for u -> 1 (series) and u small (hw log).
__device__ inline float neg_log_acc(float u) {
  float t1 = 1.0f - u;
  float se = t1 * (1.f + t1 * (0.5f + t1 * (0.33333334f + t1 * 0.25f)));
  float fl = -__logf(u);
  return (t1 < 0.015625f) ? se : fl;
}

// ============ ws layout (v3) ============
// 0       sq_e f32[2048]
// 8192    avg  f32[2048]
// 16384   hist i32[2048]
// 24576   loss double
// 32768   invZ f32[2*16384]          (128KB)
// 163840  eh_sw u16[2*1024*256]      (1MB, MFMA-frag swizzled)
// 1212416 el_sw u16[2*1024*256]      (1MB)
// 2260992 est  u16[2*1024*16384]     (67MB, [g][m][n] bf16)
#define WS_INVZ   32768
#define WS_EHSW   163840
#define WS_ELSW   1212416
#define WS_EST    2260992
#define WS_NEED3  (2260992ull + 2ull * MM * (size_t)NTOT * GG)

// ---- init A: sq_e + zero hist/loss (+ optional row-major hi/lo for fallback)
__global__ void vq_init2(const float* __restrict__ emb, float* __restrict__ sq_e,
                         float* __restrict__ avg, int* __restrict__ hist,
                         double* __restrict__ loss, u16* __restrict__ eh,
                         u16* __restrict__ el, int do_split) {
  const int row = blockIdx.x * 4 + (threadIdx.x >> 6);
  const int lane = threadIdx.x & 63;
  float4 e4 = *(const float4*)&emb[(size_t)row * DD + lane * 4];
  float s = e4.x * e4.x + e4.y * e4.y + e4.z * e4.z + e4.w * e4.w;
  s = wave_sum_f(s);
  if (do_split) {
    ushort4 h, l;
    h.x = f2bf(e4.x); l.x = f2bf(e4.x - bf2f(h.x));
    h.y = f2bf(e4.y); l.y = f2bf(e4.y - bf2f(h.y));
    h.z = f2bf(e4.z); l.z = f2bf(e4.z - bf2f(h.z));
    h.w = f2bf(e4.w); l.w = f2bf(e4.w - bf2f(h.w));
    *(ushort4*)&eh[(size_t)row * DD + lane * 4] = h;
    *(ushort4*)&el[(size_t)row * DD + lane * 4] = l;
  }
  if (lane == 0) sq_e[row] = s;
  if (blockIdx.x == 0) {
    for (int i = threadIdx.x; i < GG * MM; i += 256) { avg[i] = 0.f; hist[i] = 0; }
    if (threadIdx.x == 0) *loss = 0.0;
  }
}

// ---- init B: build swizzled hi/lo tables in MFMA-frag chunk order.
// chunk(g,ct,ks,cg,quad,l15) = B[col=ct*64+cg*16+l15][k=ks*32+quad*8 .. +8]
// linear chunk idx = (((g*16+ct)*8+ks)*4+cg)*64 + quad*16 + l15, 16B each.
__global__ void vq_init_swz(const float* __restrict__ emb, u16* __restrict__ eh_sw,
                            u16* __restrict__ el_sw) {
  int tid = blockIdx.x * 256 + threadIdx.x;   // 0..65535
  int g = tid >> 15, rem = tid & 32767;
  int col = rem >> 5, kc = rem & 31;          // kc: 8-element k-chunk
  const float* src = emb + ((size_t)(g * MM + col)) * DD + kc * 8;
  float4 fa = *(const float4*)src;
  float4 fb = *(const float4*)(src + 4);
  float f[8] = {fa.x, fa.y, fa.z, fa.w, fb.x, fb.y, fb.z, fb.w};
  u16 hi[8], lo[8];
#pragma unroll
  for (int j = 0; j < 8; ++j) {
    hi[j] = f2bf(f[j]);
    lo[j] = f2bf(f[j] - bf2f(hi[j]));
  }
  int ct = col >> 6, cg = (col >> 4) & 3, l15 = col & 15;
  int ks = kc >> 2, quad = kc & 3;
  size_t chunk = ((((size_t)g * 16 + ct) * 8 + ks) * 4 + cg) * 64 + quad * 16 + l15;
  ushort4* dh = (ushort4*)(eh_sw + chunk * 8);
  ushort4* dl = (ushort4*)(el_sw + chunk * 8);
  dh[0] = make_ushort4(hi[0], hi[1], hi[2], hi[3]);
  dh[1] = make_ushort4(hi[4], hi[5], hi[6], hi[7]);
  dl[0] = make_ushort4(lo[0], lo[1], lo[2], lo[3]);
  dl[1] = make_ushort4(lo[4], lo[5], lo[6], lo[7]);
}

// ---- main v8: R1 structure (proven traffic-optimal: grid 256, 1 block/CU,
// 8 waves x 16 rows, 64-col double-buffered tiles, x staged via LDS, est
// 256B/m per epoch) + fast-math epilogue (__expf/__logf + series; fp64
// refine guards all near-tie index decisions).
__global__ __launch_bounds__(512, 2) void vq_main3(
    const float* __restrict__ x, const float* __restrict__ emb,
    const float* __restrict__ gum, const float* __restrict__ sq_e,
    const u16* __restrict__ eh_sw, const u16* __restrict__ el_sw,
    float* __restrict__ out, u16* __restrict__ est, float* __restrict__ invZ_ws,
    int* __restrict__ hist, double* __restrict__ loss) {
  __shared__ u16 bt[2][32768];     // 2 x 64KB B tile buffers (also x-stage at start)
  __shared__ int fidx_lds[128];

  const int g = blockIdx.y;
  const int n0 = blockIdx.x * 128;
  const int t = threadIdx.x;
  const int wave = t >> 6, lane = t & 63;
  const int quad = lane >> 4, l15 = lane & 15;
  const int nw = n0 + wave * 16;   // this wave's first row

  // ---- stage this wave's 16 x-rows into LDS (xor-swizzled, conflict-free) ----
  float* xs = (float*)&bt[0][0];   // 32768 floats = 128KB, wave region = 4096
  {
    const float* xb = x + (size_t)nw * (GG * DD) + (size_t)g * DD;
#pragma unroll 4
    for (int j = 0; j < 16; ++j) {
      float4 v = *(const float4*)(xb + (size_t)j * (GG * DD) + lane * 4);
      *(float4*)&xs[wave * 4096 + j * 256 + ((lane ^ (j & 7)) << 2)] = v;
    }
  }
  // each wave reads back only its own region -> no barrier needed here

  // ---- build A fragments (1 strip x 8 k-steps, hi+lo split-bf16) ----
  bf16x8 ah[8], al[8];
#pragma unroll
  for (int ks = 0; ks < 8; ++ks) {
    int row = l15;
    int c0 = ks * 8 + quad * 2;
    const float* base = &xs[wave * 4096 + row * 256];
    float4 f0 = *(const float4*)&base[((c0 ^ (row & 7)) << 2)];
    float4 f1 = *(const float4*)&base[(((c0 + 1) ^ (row & 7)) << 2)];
    float f[8] = {f0.x, f0.y, f0.z, f0.w, f1.x, f1.y, f1.z, f1.w};
#pragma unroll
    for (int j = 0; j < 8; ++j) {
      u16 h = f2bf(f[j]);
      ah[ks][j] = (short)h;
      al[ks][j] = (short)f2bf(f[j] - bf2f(h));
    }
  }
  __syncthreads();   // xs fully consumed; bt now reusable for B tiles

  const u16* sgh = eh_sw + (size_t)g * 16 * 16384;  // 16 tiles x 32KB
  const u16* sgl = el_sw + (size_t)g * 16 * 16384;

  auto stage = [&](int ct, int buf) {
    const u16* sh = sgh + (size_t)ct * 16384;
    const u16* sl = sgl + (size_t)ct * 16384;
    u16* dh = &bt[buf][0];
    u16* dl = &bt[buf][16384];
#pragma unroll
    for (int j = 0; j < 4; ++j) {
      int slot = j * 8 + wave;   // 32 slots x 1KB per table
      async16(sh + slot * 512 + lane * 8, dh + slot * 512);
      async16(sl + slot * 512 + lane * 8, dl + slot * 512);
    }
  };

  // per-lane per-row state (4 rows: r in 0..3; row = quad*4+r)
  float Zl[4], hv[4], z1[4], z2[4];
  int hid[4], i1[4], i2[4];
#pragma unroll
  for (int i = 0; i < 4; ++i) {
    Zl[i] = 0.f; hv[i] = -INFINITY; z1[i] = -INFINITY; z2[i] = -INFINITY;
    hid[i] = 0; i1[i] = 0; i2[i] = 0;
  }

  stage(0, 0);

#pragma unroll 1
  for (int ct = 0; ct < 16; ++ct) {
    __syncthreads();                     // stage(ct) landed; prev tile reads done
    if (ct < 15) stage(ct + 1, (ct + 1) & 1);
    const u16* bh_p = &bt[ct & 1][0];
    const u16* bl_p = &bt[ct & 1][16384];
#pragma unroll 1
    for (int cg = 0; cg < 4; ++cg) {
      const int colG = ct * 64 + cg * 16 + l15;
      float sqv = sq_e[g * MM + colG];
      float gv[4];
#pragma unroll
      for (int r = 0; r < 4; ++r)
        gv[r] = gum[((size_t)(nw + quad * 4 + r) * GG + g) * MM + colG];

      f32x4 c0 = {0,0,0,0}, c1 = {0,0,0,0}, c2 = {0,0,0,0};
#pragma unroll
      for (int ks = 0; ks < 8; ++ks) {
        int off = ((ks * 4 + cg) * 64 + lane) * 8;
        bf16x8 bh = *(const bf16x8*)(bh_p + off);
        bf16x8 bl = *(const bf16x8*)(bl_p + off);
        c0 = __builtin_amdgcn_mfma_f32_16x16x32_bf16(ah[ks], bh, c0, 0, 0, 0);
        c1 = __builtin_amdgcn_mfma_f32_16x16x32_bf16(ah[ks], bl, c1, 0, 0, 0);
        c2 = __builtin_amdgcn_mfma_f32_16x16x32_bf16(al[ks], bh, c2, 0, 0, 0);
      }
      ushort4 pk;
      u16* pp = (u16*)&pk;
#pragma unroll
      for (int r = 0; r < 4; ++r) {
        float lp = 2.f * (c0[r] + c1[r] + c2[r]) - sqv + SHIFT;
        float ev = __expf(fminf(lp, 80.f));
        Zl[r] += ev;
        pp[r] = f2bf(ev);
        if (lp > hv[r]) { hv[r] = lp; hid[r] = colG; }
        float zz = lp - __logf(neg_log_acc(gv[r]));
        if (zz > z1[r]) {
          z2[r] = z1[r]; i2[r] = i1[r];
          z1[r] = zz; i1[r] = colG;
        } else if (zz > z2[r]) {
          z2[r] = zz; i2[r] = colG;
        }
      }
      // est[g][m][n] bf16, 4 consecutive n per lane
      *(ushort4*)&est[((size_t)(g * MM + colG) << 14) + nw + quad * 4] = pk;
    }
  }

  // ---- per-row finalize: reduce over the 16 l15 lanes of each quad ----
#pragma unroll 1
  for (int r = 0; r < 4; ++r) {
    const int row = wave * 16 + quad * 4 + r;
    const int n = n0 + row;
    float Zr = Zl[r], hvr = hv[r];
    int hir = hid[r];
    float v1 = z1[r], v2 = z2[r];
    int j1 = i1[r], j2 = i2[r];
#pragma unroll
    for (int o = 1; o <= 8; o <<= 1) {
      Zr += __shfl_xor(Zr, o);
      float ohv = __shfl_xor(hvr, o); int ohi = __shfl_xor(hir, o);
      if (ohv > hvr || (ohv == hvr && ohi < hir)) { hvr = ohv; hir = ohi; }
      float w1 = __shfl_xor(v1, o), w2 = __shfl_xor(v2, o);
      int k1 = __shfl_xor(j1, o), k2 = __shfl_xor(j2, o);
      if (w1 > v1 || (w1 == v1 && k1 < j1)) {
        if (v1 > w2 || (v1 == w2 && j1 < k2)) { v2 = v1; j2 = j1; }
        else { v2 = w2; j2 = k2; }
        v1 = w1; j1 = k1;
      } else if (w1 > v2 || (w1 == v2 && k1 < j2)) { v2 = w1; j2 = k1; }
    }
    int fidx = j1;
    if (v1 - v2 < REFINE_GAP) {
      // exact fp64 re-check, 16-lane parallel over d
      const float* xrow = x + (size_t)n * (GG * DD) + (size_t)g * DD;
      const float* eA = emb + ((size_t)g * MM + j1) * DD;
      const float* eB = emb + ((size_t)g * MM + j2) * DD;
      double dA = 0, sA = 0, dB = 0, sB = 0;
#pragma unroll
      for (int k = 0; k < 16; ++k) {
        int d = l15 * 16 + k;
        double xv = (double)xrow[d];
        double ea = (double)eA[d], eb = (double)eB[d];
        dA += xv * ea; sA += ea * ea;
        dB += xv * eb; sB += eb * eb;
      }
#pragma unroll
      for (int o = 1; o <= 8; o <<= 1) {
        dA += __shfl_xor(dA, o); sA += __shfl_xor(sA, o);
        dB += __shfl_xor(dB, o); sB += __shfl_xor(sB, o);
      }
      double uA = (double)gum[((size_t)n * GG + g) * MM + j1];
      double uB = (double)gum[((size_t)n * GG + g) * MM + j2];
      double zA = 2.0 * dA - sA - log(-log(uA));
      double zB = 2.0 * dB - sB - log(-log(uB));
      if (zB > zA || (zB == zA && j2 < j1)) fidx = j2;
    }
    if (l15 == 0) {
      out[OFF_I + (size_t)n * GG + g] = (float)fidx;
      atomicAdd(&hist[g * MM + hir], 1);
      invZ_ws[g * NTOT + n] = 1.f / Zr;
      fidx_lds[row] = fidx;
    }
  }
  __syncthreads();

  // ---- quantized rows + commitment-loss partial (coalesced) ----
  {
    float ls = 0.f;
#pragma unroll
    for (int j = 0; j < 16; ++j) {
      int idx = j * 512 + t;
      int row = idx >> 6, f4 = idx & 63;
      int n = n0 + row, fi = fidx_lds[row];
      float4 e4 = *(const float4*)&emb[((size_t)g * MM + fi) * DD + f4 * 4];
      float4 x4 = *(const float4*)&x[(size_t)n * (GG * DD) + (size_t)g * DD + f4 * 4];
      *(float4*)&out[OFF_Q + (size_t)n * (GG * DD) + (size_t)g * DD + f4 * 4] = e4;
      float dx = x4.x - e4.x, dy = x4.y - e4.y, dz = x4.z - e4.z, dw = x4.w - e4.w;
      ls += dx * dx + dy * dy + dz * dz + dw * dw;
    }
    ls = wave_sum_f(ls);
    if (lane == 0) atomicAdd(loss, (double)ls);
  }
}

// ---- avg_probs column reduction: avg[g][m] = sum_n est[g][m][n] * invZ[g][n]
// one block per (g,m) row; 2048 blocks x 256 thr
__global__ void vq_avg(const u16* __restrict__ est, const float* __restrict__ invZ,
                       float* __restrict__ avg) {
  int wid = blockIdx.x;                // 0..2047 = g*1024+m
  int t = threadIdx.x;
  const u16* base = est + ((size_t)wid << 14);
  const float* zp = invZ + ((wid >> 10) << 14);
  float acc = 0.f;
#pragma unroll
  for (int it = 0; it < 8; ++it) {
    int n = it * 2048 + t * 8;
    uint4 e = *(const uint4*)(base + n);   // 8 bf16
    float4 z0 = *(const float4*)(zp + n);
    float4 z1 = *(const float4*)(zp + n + 4);
    acc += bf2f((u16)(e.x & 0xffff)) * z0.x + bf2f((u16)(e.x >> 16)) * z0.y +
           bf2f((u16)(e.y & 0xffff)) * z0.z + bf2f((u16)(e.y >> 16)) * z0.w +
           bf2f((u16)(e.z & 0xffff)) * z1.x + bf2f((u16)(e.z >> 16)) * z1.y +
           bf2f((u16)(e.w & 0xffff)) * z1.z + bf2f((u16)(e.w >> 16)) * z1.w;
  }
  acc = wave_sum_f(acc);
  __shared__ float sw[4];
  if ((t & 63) == 0) sw[t >> 6] = acc;
  __syncthreads();
  if (t == 0) avg[wid] = sw[0] + sw[1] + sw[2] + sw[3];
}

// ---- finalize: entropies + loss ----
__global__ void vq_fin(const float* __restrict__ avg, const int* __restrict__ hist,
                       const double* __restrict__ loss, float* __restrict__ out) {
  int g = blockIdx.x, t = threadIdx.x;
  float cp = 0.f, pp = 0.f;
  for (int m = t; m < MM; m += 256) {
    float hp = (float)hist[g * MM + m] * (1.f / 16384.f);
    cp += hp * log2f(hp + 1e-10f);
    float ap = avg[g * MM + m] * (1.f / 16384.f);
    pp += ap * log2f(ap + 1e-10f);
  }
  cp = wave_sum_f(cp);
  pp = wave_sum_f(pp);
  __shared__ float sc[4], sp[4];
  int wave = t >> 6, lane = t & 63;
  if (lane == 0) { sc[wave] = cp; sp[wave] = pp; }
  __syncthreads();
  if (t == 0) {
    out[OFF_CP + g] = -(sc[0] + sc[1] + sc[2] + sc[3]);
    out[OFF_PP + g] = -(sp[0] + sp[1] + sp[2] + sp[3]);
    if (g == 0) out[OFF_L] = (float)(*loss * (1.0 / 8388608.0));
  }
}

// ================= fallback main (small ws) =================
__global__ __launch_bounds__(256, 3) void vq_main_fast(
    const float* __restrict__ x, const float* __restrict__ emb,
    const float* __restrict__ gum, const float* __restrict__ sq_e,
    const u16* __restrict__ eh, const u16* __restrict__ el,
    float* __restrict__ out, float* __restrict__ avg,
    int* __restrict__ hist, double* __restrict__ loss) {
  __shared__ u16 est_lds[4][16][264];
  __shared__ float colsum[MM];
  __shared__ float red[16][4][8];
  __shared__ float fin_invZ[16];
  __shared__ int fin_idx[16];

  const int g = blockIdx.y;
  const int n0 = blockIdx.x * 16;
  const int t = threadIdx.x;
  const int wave = t >> 6, lane = t & 63;
  const int quad = lane >> 4, l15 = lane & 15;
  const int wm0 = wave * 256;

  for (int i = t; i < MM; i += 256) colsum[i] = 0.f;

  bf16x8 ah[8], al[8];
  {
    const float* xr = x + (size_t)(n0 + l15) * (GG * DD) + (size_t)g * DD + quad * 8;
#pragma unroll
    for (int ks = 0; ks < 8; ++ks) {
      float4 fa = *(const float4*)(xr + ks * 32);
      float4 fb = *(const float4*)(xr + ks * 32 + 4);
      float f[8] = {fa.x, fa.y, fa.z, fa.w, fb.x, fb.y, fb.z, fb.w};
#pragma unroll
      for (int j = 0; j < 8; ++j) {
        u16 h = f2bf(f[j]);
        ah[ks][j] = (short)h;
        al[ks][j] = (short)f2bf(f[j] - bf2f(h));
      }
    }
  }
  const u16* ehb = eh + ((size_t)g * MM + wm0 + l15) * DD + quad * 8;
  const u16* elb = el + ((size_t)g * MM + wm0 + l15) * DD + quad * 8;
  const float* sqb = sq_e + g * MM + wm0 + l15;

  float Z[4] = {0.f, 0.f, 0.f, 0.f};
  float hv[4] = {-INFINITY, -INFINITY, -INFINITY, -INFINITY};
  int hid[4] = {0, 0, 0, 0};
  float z1[4] = {-INFINITY, -INFINITY, -INFINITY, -INFINITY};
  float z2[4] = {-INFINITY, -INFINITY, -INFINITY, -INFINITY};
  int i1[4] = {0, 0, 0, 0}, i2[4] = {0, 0, 0, 0};

#pragma unroll 2
  for (int tt = 0; tt < 16; ++tt) {
    float sqv = sqb[tt * 16];
    float gv[4];
#pragma unroll
    for (int r = 0; r < 4; ++r)
      gv[r] = gum[((size_t)(n0 + quad * 4 + r) * GG + g) * MM + wm0 + tt * 16 + l15];
    f32x4 a0 = {0,0,0,0}, a1 = {0,0,0,0}, a2 = {0,0,0,0};
#pragma unroll
    for (int ks = 0; ks < 8; ++ks) {
      bf16x8 bh = *(const bf16x8*)(ehb + (size_t)tt * 16 * DD + ks * 32);
      bf16x8 bl = *(const bf16x8*)(elb + (size_t)tt * 16 * DD + ks * 32);
      a0 = __builtin_amdgcn_mfma_f32_16x16x32_bf16(ah[ks], bh, a0, 0, 0, 0);
      a1 = __builtin_amdgcn_mfma_f32_16x16x32_bf16(ah[ks], bl, a1, 0, 0, 0);
      a2 = __builtin_amdgcn_mfma_f32_16x16x32_bf16(al[ks], bh, a2, 0, 0, 0);
    }
    const int colL = tt * 16 + l15;
    const int colG = wm0 + colL;
#pragma unroll
    for (int r = 0; r < 4; ++r) {
      float lp = 2.f * (a0[r] + a1[r] + a2[r]) - sqv + SHIFT;
      float ev = expf(fminf(lp, 80.f));
      Z[r] += ev;
      est_lds[wave][quad * 4 + r][colL] = f2bf(ev);
      if (lp > hv[r]) { hv[r] = lp; hid[r] = colG; }
      float zz = lp - logf(-logf(gv[r]));
      if (zz > z1[r]) { z2[r] = z1[r]; i2[r] = i1[r]; z1[r] = zz; i1[r] = colG; }
      else if (zz > z2[r]) { z2[r] = zz; i2[r] = colG; }
    }
  }
#pragma unroll
  for (int r = 0; r < 4; ++r) {
    float Zr = Z[r], hvr = hv[r];
    int hir = hid[r];
    float v1 = z1[r], v2 = z2[r];
    int j1 = i1[r], j2 = i2[r];
#pragma unroll
    for (int o = 1; o <= 8; o <<= 1) {
      Zr += __shfl_xor(Zr, o);
      float ohv = __shfl_xor(hvr, o); int ohi = __shfl_xor(hir, o);
      if (ohv > hvr || (ohv == hvr && ohi < hir)) { hvr = ohv; hir = ohi; }
      float w1 = __shfl_xor(v1, o), w2 = __shfl_xor(v2, o);
      int k1 = __shfl_xor(j1, o), k2 = __shfl_xor(j2, o);
      if (w1 > v1 || (w1 == v1 && k1 < j1)) {
        if (v1 > w2 || (v1 == w2 && j1 < k2)) { v2 = v1; j2 = j1; }
        else { v2 = w2; j2 = k2; }
        v1 = w1; j1 = k1;
      } else if (w1 > v2 || (w1 == v2 && k1 < j2)) { v2 = w1; j2 = k1; }
    }
    if (l15 == 0) {
      float* rp = red[quad * 4 + r][wave];
      rp[0] = Zr; rp[1] = hvr; rp[2] = __int_as_float(hir);
      rp[3] = v1; rp[4] = __int_as_float(j1);
      rp[5] = v2; rp[6] = __int_as_float(j2);
    }
  }
  __syncthreads();
  if (t < 16) {
    const int row = t, n = n0 + row;
    float Zf = 0.f, hvf = -INFINITY; int hif = 0;
    float v1 = -INFINITY, v2 = -INFINITY; int j1 = 0, j2 = 0;
    for (int w = 0; w < 4; ++w) {
      const float* rp = red[row][w];
      Zf += rp[0];
      float ohv = rp[1]; int ohi = __float_as_int(rp[2]);
      if (ohv > hvf || (ohv == hvf && ohi < hif)) { hvf = ohv; hif = ohi; }
      float w1 = rp[3], w2 = rp[5];
      int k1 = __float_as_int(rp[4]), k2 = __float_as_int(rp[6]);
      if (w1 > v1 || (w1 == v1 && k1 < j1)) {
        if (v1 > w2 || (v1 == w2 && j1 < k2)) { v2 = v1; j2 = j1; }
        else { v2 = w2; j2 = k2; }
        v1 = w1; j1 = k1;
      } else if (w1 > v2 || (w1 == v2 && k1 < j2)) { v2 = w1; j2 = k1; }
    }
    int fidx = j1;
    if (v1 - v2 < REFINE_GAP) {
      const float* xrow = x + (size_t)n * (GG * DD) + (size_t)g * DD;
      const float* eA = emb + ((size_t)g * MM + j1) * DD;
      const float* eB = emb + ((size_t)g * MM + j2) * DD;
      double dA = 0, sA = 0, dB = 0, sB = 0;
      for (int d = 0; d < DD; ++d) {
        double xv = xrow[d], ea = eA[d], eb = eB[d];
        dA += xv * ea; sA += ea * ea;
        dB += xv * eb; sB += eb * eb;
      }
      double uA = gum[((size_t)n * GG + g) * MM + j1];
      double uB = gum[((size_t)n * GG + g) * MM + j2];
      double zA = 2.0 * dA - sA - log(-log(uA));
      double zB = 2.0 * dB - sB - log(-log(uB));
      if (zB > zA || (zB == zA && j2 < j1)) fidx = j2;
    }
    out[OFF_I + (size_t)n * GG + g] = (float)fidx;
    atomicAdd(&hist[g * MM + hif], 1);
    fin_invZ[row] = 1.f / Zf;
    fin_idx[row] = fidx;
  }
  __syncthreads();
  {
    const int row = t >> 4, c = (t & 15) * 16;
    const int n = n0 + row, fidx = fin_idx[row];
    const float* er = emb + ((size_t)g * MM + fidx) * DD + c;
    const float* xq = x + (size_t)n * (GG * DD) + (size_t)g * DD + c;
    float* op = out + OFF_Q + (size_t)n * (GG * DD) + (size_t)g * DD + c;
    float ls = 0.f;
#pragma unroll
    for (int j = 0; j < 4; ++j) {
      float4 e4 = *(const float4*)(er + j * 4);
      float4 x4 = *(const float4*)(xq + j * 4);
      *(float4*)(op + j * 4) = e4;
      float dx = x4.x - e4.x, dy = x4.y - e4.y, dz = x4.z - e4.z, dw = x4.w - e4.w;
      ls += dx * dx + dy * dy + dz * dz + dw * dw;
    }
    ls = wave_sum_f(ls);
    if (lane == 0) atomicAdd(loss, (double)ls);
  }
  float iZ[4];
#pragma unroll
  for (int r = 0; r < 4; ++r) iZ[r] = fin_invZ[quad * 4 + r];
#pragma unroll 1
  for (int tt = 0; tt < 16; ++tt) {
    float v = 0.f;
#pragma unroll
    for (int r = 0; r < 4; ++r)
      v += bf2f(est_lds[wave][quad * 4 + r][tt * 16 + l15]) * iZ[r];
    v += __shfl_xor(v, 16);
    v += __shfl_xor(v, 32);
    if (lane < 16) colsum[wm0 + tt * 16 + lane] += v;
  }
  __syncthreads();
  for (int i = t; i < MM; i += 256) atomicAdd(&avg[g * MM + i], colsum[i]);
}

extern "C" void kernel_launch(void* const* d_in, const int* in_sizes, int n_in,
                              void* d_out, int out_size, void* d_ws, size_t ws_size,
                              hipStream_t stream) {
  const float* x = (const float*)d_in[0];
  const float* emb = (const float*)d_in[1];
  const float* gum = (const float*)d_in[2];
  float* out = (float*)d_out;

  float* sq_e = (float*)d_ws;
  float* avg = (float*)((char*)d_ws + 8192);
  int* hist = (int*)((char*)d_ws + 16384);
  double* loss = (double*)((char*)d_ws + 24576);

  if (ws_size >= WS_NEED3) {
    float* invZ = (float*)((char*)d_ws + WS_INVZ);
    u16* eh_sw = (u16*)((char*)d_ws + WS_EHSW);
    u16* el_sw = (u16*)((char*)d_ws + WS_ELSW);
    u16* est = (u16*)((char*)d_ws + WS_EST);
    vq_init2<<<512, 256, 0, stream>>>(emb, sq_e, avg, hist, loss, eh_sw, el_sw, 0);
    vq_init_swz<<<256, 256, 0, stream>>>(emb, eh_sw, el_sw);
    vq_main3<<<dim3(NTOT / 128, GG), 512, 0, stream>>>(
        x, emb, gum, sq_e, eh_sw, el_sw, out, est, invZ, hist, loss);
    vq_avg<<<2048, 256, 0, stream>>>(est, invZ, avg);
    vq_fin<<<GG, 256, 0, stream>>>(avg, hist, loss, out);
  } else {
    // fallback (needs 32KB + 2MB row-major hi/lo tables)
    u16* eh = (u16*)((char*)d_ws + 32768);
    u16* el = eh + (size_t)GG * MM * DD;
    vq_init2<<<512, 256, 0, stream>>>(emb, sq_e, avg, hist, loss, eh, el, 1);
    vq_main_fast<<<dim3(NTOT / 16, GG), 256, 0, stream>>>(
        x, emb, gum, sq_e, eh, el, out, avg, hist, loss);
    vq_fin<<<GG, 256, 0, stream>>>(avg, hist, loss, out);
  }
}

// Round 6
// 345.069 us; speedup vs baseline: 1.4144x; 1.0416x over previous
//
#include <hip/hip_runtime.h>
#include <math.h>

// Problem constants
#define NTOT 16384        // N = B*T
#define GG 2
#define MM 1024
#define DD 256

// Output layout (flat float32)
#define OFF_Q  ((size_t)0)
#define OFF_CP ((size_t)8388608)
#define OFF_PP ((size_t)8388610)
#define OFF_I  ((size_t)8388612)
#define OFF_L  ((size_t)8421380)

#define SHIFT 40.0f       // row-constant logit shift (softmax/argmax invariant)
#define REFINE_GAP 0.03f  // fp64 re-check threshold (fast-log z err << this)

typedef __attribute__((ext_vector_type(8))) short bf16x8;
typedef __attribute__((ext_vector_type(4))) float f32x4;
typedef unsigned short u16;
typedef unsigned int u32;

__device__ inline float wave_sum_f(float v) {
#pragma unroll
  for (int o = 32; o > 0; o >>= 1) v += __shfl_xor(v, o);
  return v;
}
__device__ inline u16 f2bf(float f) {
  u32 u = __float_as_uint(f);
  return (u16)((u + 0x7fffu + ((u >> 16) & 1u)) >> 16);
}
__device__ inline float bf2f(u16 h) {
  return __uint_as_float(((u32)h) << 16);
}
// async 16B global->LDS (LDS dest = wave-uniform base + lane*16)
__device__ inline void async16(const void* g, void* l) {
  __builtin_amdgcn_global_load_lds(
      (const __attribute__((address_space(1))) u32*)g,
      (__attribute__((address_space(3))) u32*)l, 16, 0, 0);
}
// -ln(u), accurate for u -> 1 (series) and u small (hw log).
__device__ inline float neg_log_acc(float u) {
  float t1 = 1.0f - u;
  float se = t1 * (1.f + t1 * (0.5f + t1 * (0.33333334f + t1 * 0.25f)));
  float fl = -__logf(u);
  return (t1 < 0.015625f) ? se : fl;
}

// ============ ws layout (v3) ============
// 0       sq_e f32[2048]
// 8192    avg  f32[2048]
// 16384   hist i32[2048]
// 24576   loss double
// 32768   invZ f32[2*16384]          (128KB)
// 163840  eh_sw u16[2*1024*256]      (1MB, MFMA-frag swizzled)
// 1212416 el_sw u16[2*1024*256]      (1MB)
// 2260992 est  u16[2*1024*16384]     (67MB, [g][m][n] bf16)
#define WS_INVZ   32768
#define WS_EHSW   163840
#define WS_ELSW   1212416
#define WS_EST    2260992
#define WS_NEED3  (2260992ull + 2ull * MM * (size_t)NTOT * GG)

// ---- init A: sq_e + zero hist/loss (+ optional row-major hi/lo for fallback)
__global__ void vq_init2(const float* __restrict__ emb, float* __restrict__ sq_e,
                         float* __restrict__ avg, int* __restrict__ hist,
                         double* __restrict__ loss, u16* __restrict__ eh,
                         u16* __restrict__ el, int do_split) {
  const int row = blockIdx.x * 4 + (threadIdx.x >> 6);
  const int lane = threadIdx.x & 63;
  float4 e4 = *(const float4*)&emb[(size_t)row * DD + lane * 4];
  float s = e4.x * e4.x + e4.y * e4.y + e4.z * e4.z + e4.w * e4.w;
  s = wave_sum_f(s);
  if (do_split) {
    ushort4 h, l;
    h.x = f2bf(e4.x); l.x = f2bf(e4.x - bf2f(h.x));
    h.y = f2bf(e4.y); l.y = f2bf(e4.y - bf2f(h.y));
    h.z = f2bf(e4.z); l.z = f2bf(e4.z - bf2f(h.z));
    h.w = f2bf(e4.w); l.w = f2bf(e4.w - bf2f(h.w));
    *(ushort4*)&eh[(size_t)row * DD + lane * 4] = h;
    *(ushort4*)&el[(size_t)row * DD + lane * 4] = l;
  }
  if (lane == 0) sq_e[row] = s;
  if (blockIdx.x == 0) {
    for (int i = threadIdx.x; i < GG * MM; i += 256) { avg[i] = 0.f; hist[i] = 0; }
    if (threadIdx.x == 0) *loss = 0.0;
  }
}

// ---- init B: build swizzled hi/lo tables in MFMA-frag chunk order.
// chunk(g,ct,ks,cg,quad,l15) = B[col=ct*64+cg*16+l15][k=ks*32+quad*8 .. +8]
// linear chunk idx = (((g*16+ct)*8+ks)*4+cg)*64 + quad*16 + l15, 16B each.
__global__ void vq_init_swz(const float* __restrict__ emb, u16* __restrict__ eh_sw,
                            u16* __restrict__ el_sw) {
  int tid = blockIdx.x * 256 + threadIdx.x;   // 0..65535
  int g = tid >> 15, rem = tid & 32767;
  int col = rem >> 5, kc = rem & 31;          // kc: 8-element k-chunk
  const float* src = emb + ((size_t)(g * MM + col)) * DD + kc * 8;
  float4 fa = *(const float4*)src;
  float4 fb = *(const float4*)(src + 4);
  float f[8] = {fa.x, fa.y, fa.z, fa.w, fb.x, fb.y, fb.z, fb.w};
  u16 hi[8], lo[8];
#pragma unroll
  for (int j = 0; j < 8; ++j) {
    hi[j] = f2bf(f[j]);
    lo[j] = f2bf(f[j] - bf2f(hi[j]));
  }
  int ct = col >> 6, cg = (col >> 4) & 3, l15 = col & 15;
  int ks = kc >> 2, quad = kc & 3;
  size_t chunk = ((((size_t)g * 16 + ct) * 8 + ks) * 4 + cg) * 64 + quad * 16 + l15;
  ushort4* dh = (ushort4*)(eh_sw + chunk * 8);
  ushort4* dl = (ushort4*)(el_sw + chunk * 8);
  dh[0] = make_ushort4(hi[0], hi[1], hi[2], hi[3]);
  dh[1] = make_ushort4(hi[4], hi[5], hi[6], hi[7]);
  dl[0] = make_ushort4(lo[0], lo[1], lo[2], lo[3]);
  dl[1] = make_ushort4(lo[4], lo[5], lo[6], lo[7]);
}

// ---- main v9: R1/R5 structure (grid 256, 1 block/CU, 8 waves x 16 rows,
// 64-col double-buffered tiles) + 2-step-deep register prefetch of gum/sq_e
// (hides the ~900cy HBM gather latency under 2 steps of MFMA+epilogue) +
// v_cvt_pk_bf16_f32 est packing (-10 VALU/step).
__global__ __launch_bounds__(512, 2) void vq_main3(
    const float* __restrict__ x, const float* __restrict__ emb,
    const float* __restrict__ gum, const float* __restrict__ sq_e,
    const u16* __restrict__ eh_sw, const u16* __restrict__ el_sw,
    float* __restrict__ out, u16* __restrict__ est, float* __restrict__ invZ_ws,
    int* __restrict__ hist, double* __restrict__ loss) {
  __shared__ u16 bt[2][32768];     // 2 x 64KB B tile buffers (also x-stage at start)
  __shared__ int fidx_lds[128];

  const int g = blockIdx.y;
  const int n0 = blockIdx.x * 128;
  const int t = threadIdx.x;
  const int wave = t >> 6, lane = t & 63;
  const int quad = lane >> 4, l15 = lane & 15;
  const int nw = n0 + wave * 16;   // this wave's first row

  // ---- stage this wave's 16 x-rows into LDS (xor-swizzled, conflict-free) ----
  float* xs = (float*)&bt[0][0];   // 32768 floats = 128KB, wave region = 4096
  {
    const float* xb = x + (size_t)nw * (GG * DD) + (size_t)g * DD;
#pragma unroll 4
    for (int j = 0; j < 16; ++j) {
      float4 v = *(const float4*)(xb + (size_t)j * (GG * DD) + lane * 4);
      *(float4*)&xs[wave * 4096 + j * 256 + ((lane ^ (j & 7)) << 2)] = v;
    }
  }
  // each wave reads back only its own region -> no barrier needed here

  // ---- build A fragments (1 strip x 8 k-steps, hi+lo split-bf16) ----
  bf16x8 ah[8], al[8];
#pragma unroll
  for (int ks = 0; ks < 8; ++ks) {
    int row = l15;
    int c0 = ks * 8 + quad * 2;
    const float* base = &xs[wave * 4096 + row * 256];
    float4 f0 = *(const float4*)&base[((c0 ^ (row & 7)) << 2)];
    float4 f1 = *(const float4*)&base[(((c0 + 1) ^ (row & 7)) << 2)];
    float f[8] = {f0.x, f0.y, f0.z, f0.w, f1.x, f1.y, f1.z, f1.w};
#pragma unroll
    for (int j = 0; j < 8; ++j) {
      u16 h = f2bf(f[j]);
      ah[ks][j] = (short)h;
      al[ks][j] = (short)f2bf(f[j] - bf2f(h));
    }
  }
  __syncthreads();   // xs fully consumed; bt now reusable for B tiles

  const u16* sgh = eh_sw + (size_t)g * 16 * 16384;  // 16 tiles x 32KB
  const u16* sgl = el_sw + (size_t)g * 16 * 16384;

  auto stage = [&](int ct, int buf) {
    const u16* sh = sgh + (size_t)ct * 16384;
    const u16* sl = sgl + (size_t)ct * 16384;
    u16* dh = &bt[buf][0];
    u16* dl = &bt[buf][16384];
#pragma unroll
    for (int j = 0; j < 4; ++j) {
      int slot = j * 8 + wave;   // 32 slots x 1KB per table
      async16(sh + slot * 512 + lane * 8, dh + slot * 512);
      async16(sl + slot * 512 + lane * 8, dl + slot * 512);
    }
  };

  // per-lane per-row state (4 rows: r in 0..3; row = quad*4+r)
  float Zl[4], hv[4], z1[4], z2[4];
  int hid[4], i1[4], i2[4];
#pragma unroll
  for (int i = 0; i < 4; ++i) {
    Zl[i] = 0.f; hv[i] = -INFINITY; z1[i] = -INFINITY; z2[i] = -INFINITY;
    hid[i] = 0; i1[i] = 0; i2[i] = 0;
  }

  stage(0, 0);

  // ---- 2-step-deep register prefetch of gum + sq_e (flat step s = ct*4+cg,
  // col = s*16 + l15; row r stride = GG*MM) ----
  const float* gumb = gum + ((size_t)(nw + quad * 4) * GG + g) * MM + l15;
  const float* sqb = sq_e + g * MM + l15;
  float gA[4], gB[4], sqA, sqB;
#pragma unroll
  for (int r = 0; r < 4; ++r) gA[r] = gumb[(size_t)r * (GG * MM)];
#pragma unroll
  for (int r = 0; r < 4; ++r) gB[r] = gumb[(size_t)r * (GG * MM) + 16];
  sqA = sqb[0];
  sqB = sqb[16];

#pragma unroll 1
  for (int ct = 0; ct < 16; ++ct) {
    __syncthreads();                     // stage(ct) landed; prev tile reads done
    if (ct < 15) stage(ct + 1, (ct + 1) & 1);
    const u16* bh_p = &bt[ct & 1][0];
    const u16* bl_p = &bt[ct & 1][16384];
#pragma unroll 1
    for (int cg = 0; cg < 4; ++cg) {
      const int s = ct * 4 + cg;
      const int colG = s * 16 + l15;
      // issue prefetch for step s+2 first (consumed 2 steps later)
      int sn = s + 2; if (sn > 63) sn = 63;
      float gN[4], sqN;
#pragma unroll
      for (int r = 0; r < 4; ++r) gN[r] = gumb[(size_t)r * (GG * MM) + sn * 16];
      sqN = sqb[sn * 16];

      f32x4 c0 = {0,0,0,0}, c1 = {0,0,0,0}, c2 = {0,0,0,0};
#pragma unroll
      for (int ks = 0; ks < 8; ++ks) {
        int off = ((ks * 4 + cg) * 64 + lane) * 8;
        bf16x8 bh = *(const bf16x8*)(bh_p + off);
        bf16x8 bl = *(const bf16x8*)(bl_p + off);
        c0 = __builtin_amdgcn_mfma_f32_16x16x32_bf16(ah[ks], bh, c0, 0, 0, 0);
        c1 = __builtin_amdgcn_mfma_f32_16x16x32_bf16(ah[ks], bl, c1, 0, 0, 0);
        c2 = __builtin_amdgcn_mfma_f32_16x16x32_bf16(al[ks], bh, c2, 0, 0, 0);
      }
      float ev[4];
#pragma unroll
      for (int r = 0; r < 4; ++r) {
        float lp = 2.f * (c0[r] + c1[r] + c2[r]) - sqA + SHIFT;
        float e = __expf(fminf(lp, 80.f));
        Zl[r] += e;
        ev[r] = e;
        if (lp > hv[r]) { hv[r] = lp; hid[r] = colG; }
        float zz = lp - __logf(neg_log_acc(gA[r]));
        if (zz > z1[r]) {
          z2[r] = z1[r]; i2[r] = i1[r];
          z1[r] = zz; i1[r] = colG;
        } else if (zz > z2[r]) {
          z2[r] = zz; i2[r] = colG;
        }
      }
      // est[g][m][n] bf16, 4 consecutive n per lane (RNE pack = f2bf)
      u32 p01, p23;
      asm("v_cvt_pk_bf16_f32 %0, %1, %2" : "=v"(p01) : "v"(ev[0]), "v"(ev[1]));
      asm("v_cvt_pk_bf16_f32 %0, %1, %2" : "=v"(p23) : "v"(ev[2]), "v"(ev[3]));
      uint2 pk2 = make_uint2(p01, p23);
      *(uint2*)&est[((size_t)(g * MM + colG) << 14) + nw + quad * 4] = pk2;
      // rotate prefetch regs
#pragma unroll
      for (int r = 0; r < 4; ++r) { gA[r] = gB[r]; gB[r] = gN[r]; }
      sqA = sqB; sqB = sqN;
    }
  }

  // ---- per-row finalize: reduce over the 16 l15 lanes of each quad ----
#pragma unroll 1
  for (int r = 0; r < 4; ++r) {
    const int row = wave * 16 + quad * 4 + r;
    const int n = n0 + row;
    float Zr = Zl[r], hvr = hv[r];
    int hir = hid[r];
    float v1 = z1[r], v2 = z2[r];
    int j1 = i1[r], j2 = i2[r];
#pragma unroll
    for (int o = 1; o <= 8; o <<= 1) {
      Zr += __shfl_xor(Zr, o);
      float ohv = __shfl_xor(hvr, o); int ohi = __shfl_xor(hir, o);
      if (ohv > hvr || (ohv == hvr && ohi < hir)) { hvr = ohv; hir = ohi; }
      float w1 = __shfl_xor(v1, o), w2 = __shfl_xor(v2, o);
      int k1 = __shfl_xor(j1, o), k2 = __shfl_xor(j2, o);
      if (w1 > v1 || (w1 == v1 && k1 < j1)) {
        if (v1 > w2 || (v1 == w2 && j1 < k2)) { v2 = v1; j2 = j1; }
        else { v2 = w2; j2 = k2; }
        v1 = w1; j1 = k1;
      } else if (w1 > v2 || (w1 == v2 && k1 < j2)) { v2 = w1; j2 = k1; }
    }
    int fidx = j1;
    if (v1 - v2 < REFINE_GAP) {
      // exact fp64 re-check, 16-lane parallel over d
      const float* xrow = x + (size_t)n * (GG * DD) + (size_t)g * DD;
      const float* eA = emb + ((size_t)g * MM + j1) * DD;
      const float* eB = emb + ((size_t)g * MM + j2) * DD;
      double dA = 0, sA = 0, dB = 0, sB = 0;
#pragma unroll
      for (int k = 0; k < 16; ++k) {
        int d = l15 * 16 + k;
        double xv = (double)xrow[d];
        double ea = (double)eA[d], eb = (double)eB[d];
        dA += xv * ea; sA += ea * ea;
        dB += xv * eb; sB += eb * eb;
      }
#pragma unroll
      for (int o = 1; o <= 8; o <<= 1) {
        dA += __shfl_xor(dA, o); sA += __shfl_xor(sA, o);
        dB += __shfl_xor(dB, o); sB += __shfl_xor(sB, o);
      }
      double uA = (double)gum[((size_t)n * GG + g) * MM + j1];
      double uB = (double)gum[((size_t)n * GG + g) * MM + j2];
      double zA = 2.0 * dA - sA - log(-log(uA));
      double zB = 2.0 * dB - sB - log(-log(uB));
      if (zB > zA || (zB == zA && j2 < j1)) fidx = j2;
    }
    if (l15 == 0) {
      out[OFF_I + (size_t)n * GG + g] = (float)fidx;
      atomicAdd(&hist[g * MM + hir], 1);
      invZ_ws[g * NTOT + n] = 1.f / Zr;
      fidx_lds[row] = fidx;
    }
  }
  __syncthreads();

  // ---- quantized rows + commitment-loss partial (coalesced) ----
  {
    float ls = 0.f;
#pragma unroll
    for (int j = 0; j < 16; ++j) {
      int idx = j * 512 + t;
      int row = idx >> 6, f4 = idx & 63;
      int n = n0 + row, fi = fidx_lds[row];
      float4 e4 = *(const float4*)&emb[((size_t)g * MM + fi) * DD + f4 * 4];
      float4 x4 = *(const float4*)&x[(size_t)n * (GG * DD) + (size_t)g * DD + f4 * 4];
      *(float4*)&out[OFF_Q + (size_t)n * (GG * DD) + (size_t)g * DD + f4 * 4] = e4;
      float dx = x4.x - e4.x, dy = x4.y - e4.y, dz = x4.z - e4.z, dw = x4.w - e4.w;
      ls += dx * dx + dy * dy + dz * dz + dw * dw;
    }
    ls = wave_sum_f(ls);
    if (lane == 0) atomicAdd(loss, (double)ls);
  }
}

// ---- avg_probs column reduction: avg[g][m] = sum_n est[g][m][n] * invZ[g][n]
// one block per (g,m) row; 2048 blocks x 256 thr
__global__ void vq_avg(const u16* __restrict__ est, const float* __restrict__ invZ,
                       float* __restrict__ avg) {
  int wid = blockIdx.x;                // 0..2047 = g*1024+m
  int t = threadIdx.x;
  const u16* base = est + ((size_t)wid << 14);
  const float* zp = invZ + ((wid >> 10) << 14);
  float acc = 0.f;
#pragma unroll
  for (int it = 0; it < 8; ++it) {
    int n = it * 2048 + t * 8;
    uint4 e = *(const uint4*)(base + n);   // 8 bf16
    float4 z0 = *(const float4*)(zp + n);
    float4 z1 = *(const float4*)(zp + n + 4);
    acc += bf2f((u16)(e.x & 0xffff)) * z0.x + bf2f((u16)(e.x >> 16)) * z0.y +
           bf2f((u16)(e.y & 0xffff)) * z0.z + bf2f((u16)(e.y >> 16)) * z0.w +
           bf2f((u16)(e.z & 0xffff)) * z1.x + bf2f((u16)(e.z >> 16)) * z1.y +
           bf2f((u16)(e.w & 0xffff)) * z1.z + bf2f((u16)(e.w >> 16)) * z1.w;
  }
  acc = wave_sum_f(acc);
  __shared__ float sw[4];
  if ((t & 63) == 0) sw[t >> 6] = acc;
  __syncthreads();
  if (t == 0) avg[wid] = sw[0] + sw[1] + sw[2] + sw[3];
}

// ---- finalize: entropies + loss ----
__global__ void vq_fin(const float* __restrict__ avg, const int* __restrict__ hist,
                       const double* __restrict__ loss, float* __restrict__ out) {
  int g = blockIdx.x, t = threadIdx.x;
  float cp = 0.f, pp = 0.f;
  for (int m = t; m < MM; m += 256) {
    float hp = (float)hist[g * MM + m] * (1.f / 16384.f);
    cp += hp * log2f(hp + 1e-10f);
    float ap = avg[g * MM + m] * (1.f / 16384.f);
    pp += ap * log2f(ap + 1e-10f);
  }
  cp = wave_sum_f(cp);
  pp = wave_sum_f(pp);
  __shared__ float sc[4], sp[4];
  int wave = t >> 6, lane = t & 63;
  if (lane == 0) { sc[wave] = cp; sp[wave] = pp; }
  __syncthreads();
  if (t == 0) {
    out[OFF_CP + g] = -(sc[0] + sc[1] + sc[2] + sc[3]);
    out[OFF_PP + g] = -(sp[0] + sp[1] + sp[2] + sp[3]);
    if (g == 0) out[OFF_L] = (float)(*loss * (1.0 / 8388608.0));
  }
}

// ================= fallback main (small ws) =================
__global__ __launch_bounds__(256, 3) void vq_main_fast(
    const float* __restrict__ x, const float* __restrict__ emb,
    const float* __restrict__ gum, const float* __restrict__ sq_e,
    const u16* __restrict__ eh, const u16* __restrict__ el,
    float* __restrict__ out, float* __restrict__ avg,
    int* __restrict__ hist, double* __restrict__ loss) {
  __shared__ u16 est_lds[4][16][264];
  __shared__ float colsum[MM];
  __shared__ float red[16][4][8];
  __shared__ float fin_invZ[16];
  __shared__ int fin_idx[16];

  const int g = blockIdx.y;
  const int n0 = blockIdx.x * 16;
  const int t = threadIdx.x;
  const int wave = t >> 6, lane = t & 63;
  const int quad = lane >> 4, l15 = lane & 15;
  const int wm0 = wave * 256;

  for (int i = t; i < MM; i += 256) colsum[i] = 0.f;

  bf16x8 ah[8], al[8];
  {
    const float* xr = x + (size_t)(n0 + l15) * (GG * DD) + (size_t)g * DD + quad * 8;
#pragma unroll
    for (int ks = 0; ks < 8; ++ks) {
      float4 fa = *(const float4*)(xr + ks * 32);
      float4 fb = *(const float4*)(xr + ks * 32 + 4);
      float f[8] = {fa.x, fa.y, fa.z, fa.w, fb.x, fb.y, fb.z, fb.w};
#pragma unroll
      for (int j = 0; j < 8; ++j) {
        u16 h = f2bf(f[j]);
        ah[ks][j] = (short)h;
        al[ks][j] = (short)f2bf(f[j] - bf2f(h));
      }
    }
  }
  const u16* ehb = eh + ((size_t)g * MM + wm0 + l15) * DD + quad * 8;
  const u16* elb = el + ((size_t)g * MM + wm0 + l15) * DD + quad * 8;
  const float* sqb = sq_e + g * MM + wm0 + l15;

  float Z[4] = {0.f, 0.f, 0.f, 0.f};
  float hv[4] = {-INFINITY, -INFINITY, -INFINITY, -INFINITY};
  int hid[4] = {0, 0, 0, 0};
  float z1[4] = {-INFINITY, -INFINITY, -INFINITY, -INFINITY};
  float z2[4] = {-INFINITY, -INFINITY, -INFINITY, -INFINITY};
  int i1[4] = {0, 0, 0, 0}, i2[4] = {0, 0, 0, 0};

#pragma unroll 2
  for (int tt = 0; tt < 16; ++tt) {
    float sqv = sqb[tt * 16];
    float gv[4];
#pragma unroll
    for (int r = 0; r < 4; ++r)
      gv[r] = gum[((size_t)(n0 + quad * 4 + r) * GG + g) * MM + wm0 + tt * 16 + l15];
    f32x4 a0 = {0,0,0,0}, a1 = {0,0,0,0}, a2 = {0,0,0,0};
#pragma unroll
    for (int ks = 0; ks < 8; ++ks) {
      bf16x8 bh = *(const bf16x8*)(ehb + (size_t)tt * 16 * DD + ks * 32);
      bf16x8 bl = *(const bf16x8*)(elb + (size_t)tt * 16 * DD + ks * 32);
      a0 = __builtin_amdgcn_mfma_f32_16x16x32_bf16(ah[ks], bh, a0, 0, 0, 0);
      a1 = __builtin_amdgcn_mfma_f32_16x16x32_bf16(ah[ks], bl, a1, 0, 0, 0);
      a2 = __builtin_amdgcn_mfma_f32_16x16x32_bf16(al[ks], bh, a2, 0, 0, 0);
    }
    const int colL = tt * 16 + l15;
    const int colG = wm0 + colL;
#pragma unroll
    for (int r = 0; r < 4; ++r) {
      float lp = 2.f * (a0[r] + a1[r] + a2[r]) - sqv + SHIFT;
      float ev = expf(fminf(lp, 80.f));
      Z[r] += ev;
      est_lds[wave][quad * 4 + r][colL] = f2bf(ev);
      if (lp > hv[r]) { hv[r] = lp; hid[r] = colG; }
      float zz = lp - logf(-logf(gv[r]));
      if (zz > z1[r]) { z2[r] = z1[r]; i2[r] = i1[r]; z1[r] = zz; i1[r] = colG; }
      else if (zz > z2[r]) { z2[r] = zz; i2[r] = colG; }
    }
  }
#pragma unroll
  for (int r = 0; r < 4; ++r) {
    float Zr = Z[r], hvr = hv[r];
    int hir = hid[r];
    float v1 = z1[r], v2 = z2[r];
    int j1 = i1[r], j2 = i2[r];
#pragma unroll
    for (int o = 1; o <= 8; o <<= 1) {
      Zr += __shfl_xor(Zr, o);
      float ohv = __shfl_xor(hvr, o); int ohi = __shfl_xor(hir, o);
      if (ohv > hvr || (ohv == hvr && ohi < hir)) { hvr = ohv; hir = ohi; }
      float w1 = __shfl_xor(v1, o), w2 = __shfl_xor(v2, o);
      int k1 = __shfl_xor(j1, o), k2 = __shfl_xor(j2, o);
      if (w1 > v1 || (w1 == v1 && k1 < j1)) {
        if (v1 > w2 || (v1 == w2 && j1 < k2)) { v2 = v1; j2 = j1; }
        else { v2 = w2; j2 = k2; }
        v1 = w1; j1 = k1;
      } else if (w1 > v2 || (w1 == v2 && k1 < j2)) { v2 = w1; j2 = k1; }
    }
    if (l15 == 0) {
      float* rp = red[quad * 4 + r][wave];
      rp[0] = Zr; rp[1] = hvr; rp[2] = __int_as_float(hir);
      rp[3] = v1; rp[4] = __int_as_float(j1);
      rp[5] = v2; rp[6] = __int_as_float(j2);
    }
  }
  __syncthreads();
  if (t < 16) {
    const int row = t, n = n0 + row;
    float Zf = 0.f, hvf = -INFINITY; int hif = 0;
    float v1 = -INFINITY, v2 = -INFINITY; int j1 = 0, j2 = 0;
    for (int w = 0; w < 4; ++w) {
      const float* rp = red[row][w];
      Zf += rp[0];
      float ohv = rp[1]; int ohi = __float_as_int(rp[2]);
      if (ohv > hvf || (ohv == hvf && ohi < hif)) { hvf = ohv; hif = ohi; }
      float w1 = rp[3], w2 = rp[5];
      int k1 = __float_as_int(rp[4]), k2 = __float_as_int(rp[6]);
      if (w1 > v1 || (w1 == v1 && k1 < j1)) {
        if (v1 > w2 || (v1 == w2 && j1 < k2)) { v2 = v1; j2 = j1; }
        else { v2 = w2; j2 = k2; }
        v1 = w1; j1 = k1;
      } else if (w1 > v2 || (w1 == v2 && k1 < j2)) { v2 = w1; j2 = k1; }
    }
    int fidx = j1;
    if (v1 - v2 < REFINE_GAP) {
      const float* xrow = x + (size_t)n * (GG * DD) + (size_t)g * DD;
      const float* eA = emb + ((size_t)g * MM + j1) * DD;
      const float* eB = emb + ((size_t)g * MM + j2) * DD;
      double dA = 0, sA = 0, dB = 0, sB = 0;
      for (int d = 0; d < DD; ++d) {
        double xv = xrow[d], ea = eA[d], eb = eB[d];
        dA += xv * ea; sA += ea * ea;
        dB += xv * eb; sB += eb * eb;
      }
      double uA = gum[((size_t)n * GG + g) * MM + j1];
      double uB = gum[((size_t)n * GG + g) * MM + j2];
      double zA = 2.0 * dA - sA - log(-log(uA));
      double zB = 2.0 * dB - sB - log(-log(uB));
      if (zB > zA || (zB == zA && j2 < j1)) fidx = j2;
    }
    out[OFF_I + (size_t)n * GG + g] = (float)fidx;
    atomicAdd(&hist[g * MM + hif], 1);
    fin_invZ[row] = 1.f / Zf;
    fin_idx[row] = fidx;
  }
  __syncthreads();
  {
    const int row = t >> 4, c = (t & 15) * 16;
    const int n = n0 + row, fidx = fin_idx[row];
    const float* er = emb + ((size_t)g * MM + fidx) * DD + c;
    const float* xq = x + (size_t)n * (GG * DD) + (size_t)g * DD + c;
    float* op = out + OFF_Q + (size_t)n * (GG * DD) + (size_t)g * DD + c;
    float ls = 0.f;
#pragma unroll
    for (int j = 0; j < 4; ++j) {
      float4 e4 = *(const float4*)(er + j * 4);
      float4 x4 = *(const float4*)(xq + j * 4);
      *(float4*)(op + j * 4) = e4;
      float dx = x4.x - e4.x, dy = x4.y - e4.y, dz = x4.z - e4.z, dw = x4.w - e4.w;
      ls += dx * dx + dy * dy + dz * dz + dw * dw;
    }
    ls = wave_sum_f(ls);
    if (lane == 0) atomicAdd(loss, (double)ls);
  }
  float iZ[4];
#pragma unroll
  for (int r = 0; r < 4; ++r) iZ[r] = fin_invZ[quad * 4 + r];
#pragma unroll 1
  for (int tt = 0; tt < 16; ++tt) {
    float v = 0.f;
#pragma unroll
    for (int r = 0; r < 4; ++r)
      v += bf2f(est_lds[wave][quad * 4 + r][tt * 16 + l15]) * iZ[r];
    v += __shfl_xor(v, 16);
    v += __shfl_xor(v, 32);
    if (lane < 16) colsum[wm0 + tt * 16 + lane] += v;
  }
  __syncthreads();
  for (int i = t; i < MM; i += 256) atomicAdd(&avg[g * MM + i], colsum[i]);
}

extern "C" void kernel_launch(void* const* d_in, const int* in_sizes, int n_in,
                              void* d_out, int out_size, void* d_ws, size_t ws_size,
                              hipStream_t stream) {
  const float* x = (const float*)d_in[0];
  const float* emb = (const float*)d_in[1];
  const float* gum = (const float*)d_in[2];
  float* out = (float*)d_out;

  float* sq_e = (float*)d_ws;
  float* avg = (float*)((char*)d_ws + 8192);
  int* hist = (int*)((char*)d_ws + 16384);
  double* loss = (double*)((char*)d_ws + 24576);

  if (ws_size >= WS_NEED3) {
    float* invZ = (float*)((char*)d_ws + WS_INVZ);
    u16* eh_sw = (u16*)((char*)d_ws + WS_EHSW);
    u16* el_sw = (u16*)((char*)d_ws + WS_ELSW);
    u16* est = (u16*)((char*)d_ws + WS_EST);
    vq_init2<<<512, 256, 0, stream>>>(emb, sq_e, avg, hist, loss, eh_sw, el_sw, 0);
    vq_init_swz<<<256, 256, 0, stream>>>(emb, eh_sw, el_sw);
    vq_main3<<<dim3(NTOT / 128, GG), 512, 0, stream>>>(
        x, emb, gum, sq_e, eh_sw, el_sw, out, est, invZ, hist, loss);
    vq_avg<<<2048, 256, 0, stream>>>(est, invZ, avg);
    vq_fin<<<GG, 256, 0, stream>>>(avg, hist, loss, out);
  } else {
    // fallback (needs 32KB + 2MB row-major hi/lo tables)
    u16* eh = (u16*)((char*)d_ws + 32768);
    u16* el = eh + (size_t)GG * MM * DD;
    vq_init2<<<512, 256, 0, stream>>>(emb, sq_e, avg, hist, loss, eh, el, 1);
    vq_main_fast<<<dim3(NTOT / 16, GG), 256, 0, stream>>>(
        x, emb, gum, sq_e, eh, el, out, avg, hist, loss);
    vq_fin<<<GG, 256, 0, stream>>>(avg, hist, loss, out);
  }
}